// Round 8
// baseline (939.312 us; speedup 1.0000x reference)
//
#include <hip/hip_runtime.h>
#include <hip/hip_bf16.h>

#define AS1 __attribute__((address_space(1)))
#define AS3 __attribute__((address_space(3)))

typedef __attribute__((ext_vector_type(8))) short short8;
typedef __attribute__((ext_vector_type(4))) float f32x4;

constexpr int BB = 4, TT = 768, DDIM = 512, LL = 6, VV = 50304, FF = 2048;
constexpr int MM = BB * TT;  // 3072 rows of the activation matrix

// ---------- helpers ----------
__device__ inline unsigned short f2b(float f) {
  union { float f; unsigned u; } a; a.f = f;
  unsigned u = a.u;
  return (unsigned short)((u + 0x7FFFu + ((u >> 16) & 1u)) >> 16);  // RNE
}
__device__ inline float b2f(unsigned short u) {
  union { unsigned u; float f; } a; a.u = ((unsigned)u) << 16; return a.f;
}

// ---------- fused f32 -> bf16 convert of all 5 weight tensors ----------
constexpr size_t CW0 = (size_t)VV * DDIM;                  // wte
constexpr size_t CW1 = CW0 + (size_t)LL * 3 * DDIM * DDIM; // + c_attn_w
constexpr size_t CW2 = CW1 + (size_t)LL * DDIM * DDIM;     // + c_proj_w
constexpr size_t CW3 = CW2 + (size_t)LL * FF * DDIM;       // + fc_w
constexpr size_t CW4 = CW3 + (size_t)LL * DDIM * FF;       // + fc2_w

__global__ void cvt_all(const float* __restrict__ wte, const float* __restrict__ aw,
                        const float* __restrict__ pw, const float* __restrict__ fw,
                        const float* __restrict__ f2w, ushort* __restrict__ out) {
  size_t i = ((size_t)blockIdx.x * 256 + threadIdx.x) * 4;
  if (i >= CW4) return;
  const float* src; size_t base;
  if (i < CW0)      { src = wte; base = 0; }
  else if (i < CW1) { src = aw;  base = CW0; }
  else if (i < CW2) { src = pw;  base = CW1; }
  else if (i < CW3) { src = fw;  base = CW2; }
  else              { src = f2w; base = CW3; }
  float4 v = *(const float4*)(src + (i - base));
  ushort4 o = { f2b(v.x), f2b(v.y), f2b(v.z), f2b(v.w) };
  *(ushort4*)(out + i) = o;
}

// ---------- embedding: xb = bf16(wte[idx] + wpe[t]) ----------
__global__ void embed_kernel(const int* __restrict__ idx, const float* __restrict__ wte,
                             const float* __restrict__ wpe, ushort* __restrict__ xb) {
  int row = blockIdx.x;
  int t = row % TT;
  int tok = idx[row];
  int c = threadIdx.x * 4;
  float4 a = *(const float4*)(wte + (size_t)tok * DDIM + c);
  float4 p = *(const float4*)(wpe + (size_t)t * DDIM + c);
  a.x += p.x; a.y += p.y; a.z += p.z; a.w += p.w;
  ushort4 o = { f2b(a.x), f2b(a.y), f2b(a.z), f2b(a.w) };
  *(ushort4*)(xb + (size_t)row * DDIM + c) = o;
}

// ---------- m97-geometry GEMM: 128x128, BK=32, 4 waves, dbuf 2-phase ----------
// C[M,N] = A[M,K](bf16) * Bw[N,K]^T(bf16) [+bias] [relu]; out f32 or bf16.
// 32KB LDS -> 5 blocks/CU; wave tile 64x64 -> 16 MFMA : 8 ds_read per K-step.
// SWZ=1: 1D grid XCD-chunked (grid % 8 == 0 -> bijective).
template <int RELU, int OUTBF16, int BIAS, int SWZ>
__global__ __launch_bounds__(256) void gemm97(
    const ushort* __restrict__ A, const ushort* __restrict__ Bw,
    const float* __restrict__ bias, void* __restrict__ Cv, int Ndim, int K) {
  __shared__ ushort sA[2][128 * 32];
  __shared__ ushort sB[2][128 * 32];
  const int tid = threadIdx.x;
  const int wid = tid >> 6, lane = tid & 63;
  int m0, n0;
  if (SWZ) {
    constexpr int MT = MM / 128;
    int id = blockIdx.x;
    int v = (id >> 3) + (id & 7) * ((int)gridDim.x >> 3);
    m0 = (v % MT) * 128;       // same-B blocks consecutive per XCD
    n0 = (v / MT) * 128;
  } else {
    m0 = blockIdx.y * 128;
    n0 = blockIdx.x * 128;
  }
  const int wm = (wid >> 1) * 64, wn = (wid & 1) * 64;

  f32x4 zero = {0.f, 0.f, 0.f, 0.f};
  f32x4 acc[4][4];
#pragma unroll
  for (int i = 0; i < 4; i++)
#pragma unroll
    for (int j = 0; j < 4; j++) acc[i][j] = zero;

  const int r4 = tid >> 2;
  const int c8 = (tid & 3) * 8;
  const ushort* gA = A + (size_t)(m0 + r4) * K + c8;
  const ushort* gB = Bw + (size_t)(n0 + r4) * K + c8;
  const size_t K64 = (size_t)64 * K;

  auto stage = [&](int buf, int kk) {
    const ushort* a0 = gA + kk * 32;
    const ushort* b0 = gB + kk * 32;
    ushort* dA = &sA[buf][0] + wid * 512;
    ushort* dB = &sB[buf][0] + wid * 512;
#pragma unroll
    for (int i = 0; i < 2; i++)
      __builtin_amdgcn_global_load_lds((const AS1 void*)(a0 + (size_t)i * K64),
                                       (AS3 void*)(dA + i * 2048), 16, 0, 0);
#pragma unroll
    for (int i = 0; i < 2; i++)
      __builtin_amdgcn_global_load_lds((const AS1 void*)(b0 + (size_t)i * K64),
                                       (AS3 void*)(dB + i * 2048), 16, 0, 0);
  };

  const int fr = lane & 15;
  const int fk = (lane >> 4) * 8;
  const int nK = K >> 5;
  stage(0, 0);
  __syncthreads();
  int buf = 0;
  for (int kk = 0; kk < nK; ++kk) {
    if (kk + 1 < nK) stage(buf ^ 1, kk + 1);
    const ushort* pa0 = &sA[buf][0] + (wm + fr) * 32 + fk;
    const ushort* pb0 = &sB[buf][0] + (wn + fr) * 32 + fk;
    short8 af[4], bf[4];
#pragma unroll
    for (int i = 0; i < 4; i++) af[i] = *(const short8*)(pa0 + i * 16 * 32);
#pragma unroll
    for (int j = 0; j < 4; j++) bf[j] = *(const short8*)(pb0 + j * 16 * 32);
#pragma unroll
    for (int i = 0; i < 4; i++)
#pragma unroll
      for (int j = 0; j < 4; j++)
        acc[i][j] = __builtin_amdgcn_mfma_f32_16x16x32_bf16(af[i], bf[j], acc[i][j], 0, 0, 0);
    __syncthreads();
    buf ^= 1;
  }

  const int cr = (lane >> 4) * 4;
  const int cc = lane & 15;
#pragma unroll
  for (int j = 0; j < 4; j++) {
    const int gcol = n0 + wn + j * 16 + cc;
    const float bv = BIAS ? bias[gcol] : 0.0f;
#pragma unroll
    for (int i = 0; i < 4; i++) {
      const int grow = m0 + wm + i * 16 + cr;
#pragma unroll
      for (int rr = 0; rr < 4; ++rr) {
        float v = acc[i][j][rr] + bv;
        if (RELU) v = fmaxf(v, 0.0f);
        if (OUTBF16)
          ((ushort*)Cv)[(size_t)(grow + rr) * Ndim + gcol] = f2b(v);
        else
          ((float*)Cv)[(size_t)(grow + rr) * Ndim + gcol] = v;
      }
    }
  }
}

// ---------- proj/fc2 GEMM: 64x64, BK=64, swizzled LDS, split-K=2 ----------
template <int SPLITK>
__global__ __launch_bounds__(256) void gemm_bt64(
    const ushort* __restrict__ A, const ushort* __restrict__ Bw,
    const float* __restrict__ bias, ushort* __restrict__ Cv, int Ndim, int K) {
  constexpr int BM = 64, BN = 64;
  constexpr int MI = 2, NJ = 2;
  __shared__ ushort sA[2][BM * 64];
  __shared__ ushort sB[2][BN * 64];
  const int tid = threadIdx.x;
  const int wid = tid >> 6, lane = tid & 63;
  const int m0 = blockIdx.y * BM, n0 = blockIdx.x * BN;
  const int kchunk = K / SPLITK;
  const int ks0 = blockIdx.z * kchunk;
  const int wm = (wid >> 1) * 32, wn = (wid & 1) * 32;

  f32x4 zero = {0.f, 0.f, 0.f, 0.f};
  f32x4 acc[MI][NJ];
#pragma unroll
  for (int i = 0; i < MI; i++)
#pragma unroll
    for (int j = 0; j < NJ; j++) acc[i][j] = zero;

  const int r = tid >> 3;
  const int cg = ((tid & 7) ^ (r & 7)) * 8;
  const ushort* gA = A + (size_t)(m0 + r) * K + ks0 + cg;
  const ushort* gB = Bw + (size_t)(n0 + r) * K + ks0 + cg;

  auto stage = [&](int buf, int kk) {
    const ushort* a0 = gA + kk * 64;
    const ushort* b0 = gB + kk * 64;
    ushort* dA = &sA[buf][0] + wid * 512;
    ushort* dB = &sB[buf][0] + wid * 512;
#pragma unroll
    for (int p = 0; p < 2; p++)
      __builtin_amdgcn_global_load_lds((const AS1 void*)(a0 + (size_t)p * 32 * K),
                                       (AS3 void*)(dA + p * 2048), 16, 0, 0);
#pragma unroll
    for (int p = 0; p < 2; p++)
      __builtin_amdgcn_global_load_lds((const AS1 void*)(b0 + (size_t)p * 32 * K),
                                       (AS3 void*)(dB + p * 2048), 16, 0, 0);
  };

  const int fr = lane & 15;
  const int fk = (lane >> 4) * 8;
  auto ldfrag = [&](const ushort* s, int rowbase, int sub) -> short8 {
    const int row = rowbase + fr;
    const int off = row * 128 + ((sub * 64 + fk * 2) ^ ((fr & 7) << 4));
    return *(const short8*)((const char*)s + off);
  };

  const int nK = kchunk >> 6;
  stage(0, 0);
  __syncthreads();
  int buf = 0;
  for (int kk = 0; kk < nK; ++kk) {
    if (kk + 1 < nK) stage(buf ^ 1, kk + 1);
    short8 af[MI][2], bf[NJ][2];
#pragma unroll
    for (int i = 0; i < MI; i++)
#pragma unroll
      for (int s = 0; s < 2; s++) af[i][s] = ldfrag(&sA[buf][0], wm + i * 16, s);
#pragma unroll
    for (int j = 0; j < NJ; j++)
#pragma unroll
      for (int s = 0; s < 2; s++) bf[j][s] = ldfrag(&sB[buf][0], wn + j * 16, s);
#pragma unroll
    for (int i = 0; i < MI; i++)
#pragma unroll
      for (int j = 0; j < NJ; j++)
#pragma unroll
        for (int s = 0; s < 2; s++)
          acc[i][j] = __builtin_amdgcn_mfma_f32_16x16x32_bf16(af[i][s], bf[j][s], acc[i][j], 0, 0, 0);
    __syncthreads();
    buf ^= 1;
  }

  const int cr = (lane >> 4) * 4;
  const int cc = lane & 15;
  ushort* Cb = Cv + (size_t)blockIdx.z * MM * Ndim;
#pragma unroll
  for (int j = 0; j < NJ; j++) {
    const int gcol = n0 + wn + j * 16 + cc;
    const float bv = (blockIdx.z == 0) ? bias[gcol] : 0.0f;
#pragma unroll
    for (int i = 0; i < MI; i++) {
      const int grow = m0 + wm + i * 16 + cr;
#pragma unroll
      for (int rr = 0; rr < 4; ++rr)
        Cb[(size_t)(grow + rr) * Ndim + gcol] = f2b(acc[i][j][rr] + bv);
    }
  }
}

// ---------- MFMA fused causal attention ----------
__device__ inline short8 lds_swz_read(const ushort* base, int row, int elem) {
  return *(const short8*)((const char*)base + row * 128 + ((elem * 2) ^ ((row & 7) << 4)));
}

__global__ __launch_bounds__(256) void attn_mfma(const ushort* __restrict__ qkv,
                                                 ushort* __restrict__ yb) {
  __shared__ ushort sK[64 * 64];
  __shared__ ushort sVT[64 * 64];
  __shared__ ushort sP[4 * 16 * 64];
  const int tid = threadIdx.x;
  const int wid = tid >> 6, lane = tid & 63;
  const int qt = blockIdx.x;
  const int b = blockIdx.y >> 3, h = blockIdx.y & 7;
  const int q0 = qt * 64;
  const int qw = q0 + wid * 16;

  const int fr = lane & 15;
  const int fk = (lane >> 4) * 8;
  ushort* sPw = sP + wid * 16 * 64;

  short8 qf[2];
  {
    const ushort* qp = qkv + (size_t)(b * TT + qw + fr) * 1536 + h * 64;
    qf[0] = *(const short8*)(qp + fk);
    qf[1] = *(const short8*)(qp + 32 + fk);
  }

  const int r4 = tid >> 2;           // K staging: row, 16-elem slice
  const int c32 = (tid & 3) * 16;
  const int kb = (tid >> 4) * 4;     // V staging: 4 k-rows
  const int db = (tid & 15) * 4;     // 4 d-cols

  f32x4 zero = {0.f, 0.f, 0.f, 0.f};
  f32x4 acc[4] = {zero, zero, zero, zero};
  float mrow[4] = {-INFINITY, -INFINITY, -INFINITY, -INFINITY};
  float lrow[4] = {0.f, 0.f, 0.f, 0.f};

  for (int kt = 0; kt <= qt; ++kt) {
    __syncthreads();
    const int k0 = kt * 64;
    {  // K tile: swizzled b128 writes
      const ushort* kp = qkv + (size_t)(b * TT + k0 + r4) * 1536 + 512 + h * 64 + c32;
      short8 kv0 = *(const short8*)kp;
      short8 kv1 = *(const short8*)(kp + 8);
      char* skb = (char*)sK + r4 * 128;
      *(short8*)(skb + ((c32 * 2) ^ ((r4 & 7) << 4))) = kv0;
      *(short8*)(skb + ((c32 * 2 + 16) ^ ((r4 & 7) << 4))) = kv1;
      // V^T tile: 4x4 in-register transpose, 4x ds_write_b64
      const ushort* vp = qkv + (size_t)(b * TT + k0 + kb) * 1536 + 1024 + h * 64 + db;
      ushort4 L0 = *(const ushort4*)vp;
      ushort4 L1 = *(const ushort4*)(vp + 1536);
      ushort4 L2 = *(const ushort4*)(vp + 3072);
      ushort4 L3 = *(const ushort4*)(vp + 4608);
      ushort4 c0 = { L0.x, L1.x, L2.x, L3.x };
      ushort4 c1 = { L0.y, L1.y, L2.y, L3.y };
      ushort4 c2 = { L0.z, L1.z, L2.z, L3.z };
      ushort4 c3 = { L0.w, L1.w, L2.w, L3.w };
      *(ushort4*)((char*)sVT + (db + 0) * 128 + ((kb * 2) ^ (((db + 0) & 7) << 4))) = c0;
      *(ushort4*)((char*)sVT + (db + 1) * 128 + ((kb * 2) ^ (((db + 1) & 7) << 4))) = c1;
      *(ushort4*)((char*)sVT + (db + 2) * 128 + ((kb * 2) ^ (((db + 2) & 7) << 4))) = c2;
      *(ushort4*)((char*)sVT + (db + 3) * 128 + ((kb * 2) ^ (((db + 3) & 7) << 4))) = c3;
    }
    __syncthreads();

    f32x4 sfr[4];
#pragma unroll
    for (int j = 0; j < 4; j++) {
      short8 kb0 = lds_swz_read(sK, j * 16 + fr, fk);
      short8 kb1 = lds_swz_read(sK, j * 16 + fr, 32 + fk);
      f32x4 s = __builtin_amdgcn_mfma_f32_16x16x32_bf16(qf[0], kb0, zero, 0, 0, 0);
      s = __builtin_amdgcn_mfma_f32_16x16x32_bf16(qf[1], kb1, s, 0, 0, 0);
      sfr[j] = s * 0.125f;
    }
    if (kt == qt) {
#pragma unroll
      for (int j = 0; j < 4; j++)
#pragma unroll
        for (int rr = 0; rr < 4; ++rr)
          if (j * 16 + fr > wid * 16 + (lane >> 4) * 4 + rr) sfr[j][rr] = -INFINITY;
    }

    float scl[4];
#pragma unroll
    for (int rr = 0; rr < 4; ++rr) {
      float t = fmaxf(fmaxf(sfr[0][rr], sfr[1][rr]), fmaxf(sfr[2][rr], sfr[3][rr]));
      t = fmaxf(t, __shfl_xor(t, 1));
      t = fmaxf(t, __shfl_xor(t, 2));
      t = fmaxf(t, __shfl_xor(t, 4));
      t = fmaxf(t, __shfl_xor(t, 8));
      const float mnew = fmaxf(mrow[rr], t);
      scl[rr] = __expf(mrow[rr] - mnew);
      mrow[rr] = mnew;
      float ps = 0.f;
#pragma unroll
      for (int j = 0; j < 4; j++) {
        float p = __expf(sfr[j][rr] - mnew);
        sfr[j][rr] = p;
        ps += p;
      }
      ps += __shfl_xor(ps, 1);
      ps += __shfl_xor(ps, 2);
      ps += __shfl_xor(ps, 4);
      ps += __shfl_xor(ps, 8);
      lrow[rr] = lrow[rr] * scl[rr] + ps;
    }

#pragma unroll
    for (int j = 0; j < 4; j++)
#pragma unroll
      for (int rr = 0; rr < 4; ++rr) {
        int q = (lane >> 4) * 4 + rr, k = j * 16 + fr;
        *(ushort*)((char*)sPw + q * 128 + ((k * 2) ^ ((q & 7) << 4))) = f2b(sfr[j][rr]);
      }

#pragma unroll
    for (int f = 0; f < 4; f++)
#pragma unroll
      for (int rr = 0; rr < 4; ++rr) acc[f][rr] *= scl[rr];

    short8 pa0 = lds_swz_read(sPw, fr, fk);
    short8 pa1 = lds_swz_read(sPw, fr, 32 + fk);
#pragma unroll
    for (int f = 0; f < 4; f++) {
      short8 vb0 = lds_swz_read(sVT, f * 16 + fr, fk);
      short8 vb1 = lds_swz_read(sVT, f * 16 + fr, 32 + fk);
      acc[f] = __builtin_amdgcn_mfma_f32_16x16x32_bf16(pa0, vb0, acc[f], 0, 0, 0);
      acc[f] = __builtin_amdgcn_mfma_f32_16x16x32_bf16(pa1, vb1, acc[f], 0, 0, 0);
    }
  }

#pragma unroll
  for (int rr = 0; rr < 4; ++rr) {
    const float inv = 1.0f / lrow[rr];
    const int token = b * TT + qw + (lane >> 4) * 4 + rr;
    ushort* yp = yb + (size_t)token * DDIM + h * 64 + fr;
#pragma unroll
    for (int f = 0; f < 4; f++) yp[f * 16] = f2b(acc[f][rr] * inv);
  }
}

// ---------- fused residual add (+ S bf16 split-K planes) + LayerNorm ----------
// Residual stream is bf16 (post-LN values, unit-scale; rounding absorbed by LN).
template <int S>
__global__ __launch_bounds__(256) void add_ln(const ushort* __restrict__ xr,
                                              const ushort* __restrict__ y,
                                              const float* __restrict__ w,
                                              const float* __restrict__ bb,
                                              ushort* __restrict__ xo) {
  const int row = blockIdx.x * 4 + (threadIdx.x >> 6);
  const int lane = threadIdx.x & 63;
  const size_t base = (size_t)row * DDIM + lane * 8;
  short8 xv = *(const short8*)(xr + base);
  f32x4 a0 = { b2f((unsigned short)xv[0]), b2f((unsigned short)xv[1]),
               b2f((unsigned short)xv[2]), b2f((unsigned short)xv[3]) };
  f32x4 a1 = { b2f((unsigned short)xv[4]), b2f((unsigned short)xv[5]),
               b2f((unsigned short)xv[6]), b2f((unsigned short)xv[7]) };
#pragma unroll
  for (int s = 0; s < S; ++s) {
    short8 v = *(const short8*)(y + (size_t)s * MM * DDIM + base);
    f32x4 p0 = { b2f((unsigned short)v[0]), b2f((unsigned short)v[1]),
                 b2f((unsigned short)v[2]), b2f((unsigned short)v[3]) };
    f32x4 p1 = { b2f((unsigned short)v[4]), b2f((unsigned short)v[5]),
                 b2f((unsigned short)v[6]), b2f((unsigned short)v[7]) };
    a0 += p0; a1 += p1;
  }
  float sm = (a0[0] + a0[1] + a0[2] + a0[3]) + (a1[0] + a1[1] + a1[2] + a1[3]);
  f32x4 q0 = a0 * a0, q1 = a1 * a1;
  float ss = (q0[0] + q0[1] + q0[2] + q0[3]) + (q1[0] + q1[1] + q1[2] + q1[3]);
#pragma unroll
  for (int o = 1; o < 64; o <<= 1) {
    sm += __shfl_xor(sm, o);
    ss += __shfl_xor(ss, o);
  }
  const float mu = sm * (1.0f / DDIM);
  const float var = ss * (1.0f / DDIM) - mu * mu;
  const float rs = rsqrtf(var + 1e-5f);
  const int c = lane * 8;
  f32x4 w0 = *(const f32x4*)(w + c), w1 = *(const f32x4*)(w + c + 4);
  f32x4 b0 = *(const f32x4*)(bb + c), b1 = *(const f32x4*)(bb + c + 4);
  f32x4 o0 = (a0 - mu) * rs * w0 + b0;
  f32x4 o1 = (a1 - mu) * rs * w1 + b1;
  short8 u;
  u[0] = (short)f2b(o0[0]); u[1] = (short)f2b(o0[1]);
  u[2] = (short)f2b(o0[2]); u[3] = (short)f2b(o0[3]);
  u[4] = (short)f2b(o1[0]); u[5] = (short)f2b(o1[1]);
  u[6] = (short)f2b(o1[2]); u[7] = (short)f2b(o1[3]);
  *(short8*)(xo + base) = u;
}

// ---------- launch ----------
extern "C" void kernel_launch(void* const* d_in, const int* in_sizes, int n_in,
                              void* d_out, int out_size, void* d_ws, size_t ws_size,
                              hipStream_t stream) {
  const int*   idx  = (const int*)d_in[0];
  const float* wte  = (const float*)d_in[1];
  const float* wpe  = (const float*)d_in[2];
  const float* aw   = (const float*)d_in[3];
  const float* ab   = (const float*)d_in[4];
  const float* pw   = (const float*)d_in[5];
  const float* pb   = (const float*)d_in[6];
  const float* fw   = (const float*)d_in[7];
  const float* fb   = (const float*)d_in[8];
  const float* f2w  = (const float*)d_in[9];
  const float* f2bi = (const float*)d_in[10];
  const float* l1w  = (const float*)d_in[11];
  const float* l1b  = (const float*)d_in[12];
  const float* l2w  = (const float*)d_in[13];
  const float* l2b  = (const float*)d_in[14];
  const float* lnfw = (const float*)d_in[15];
  const float* lnfb = (const float*)d_in[16];

  char* ws = (char*)d_ws;
  size_t off = 0;
  auto take = [&](size_t bytes) -> void* {
    void* p = ws + off;
    off += (bytes + 255) & ~(size_t)255;
    return p;
  };
  ushort* wte_b = (ushort*)take((size_t)VV * DDIM * 2);
  ushort* aw_b  = (ushort*)take((size_t)LL * 3 * DDIM * DDIM * 2);
  ushort* pw_b  = (ushort*)take((size_t)LL * DDIM * DDIM * 2);
  ushort* fw_b  = (ushort*)take((size_t)LL * FF * DDIM * 2);
  ushort* f2w_b = (ushort*)take((size_t)LL * DDIM * FF * 2);
  ushort* xb    = (ushort*)take((size_t)MM * DDIM * 2);
  ushort* qkv_b = (ushort*)take((size_t)MM * 3 * DDIM * 2);
  ushort* yb    = (ushort*)take((size_t)MM * DDIM * 2);
  ushort* tmp_b = (ushort*)take((size_t)2 * MM * DDIM * 2);  // 2 bf16 split-K planes
  ushort* hb    = (ushort*)take((size_t)MM * FF * 2);

  cvt_all<<<dim3((unsigned)(CW4 / 4 / 256)), dim3(256), 0, stream>>>(
      wte, aw, pw, fw, f2w, wte_b);

  embed_kernel<<<dim3(MM), dim3(128), 0, stream>>>(idx, wte, wpe, xb);

  for (int l = 0; l < LL; ++l) {
    gemm97<0, 1, 1, 0><<<dim3(12, 24), dim3(256), 0, stream>>>(
        xb, aw_b + (size_t)l * 3 * DDIM * DDIM, ab + (size_t)l * 3 * DDIM, qkv_b, 3 * DDIM, DDIM);
    attn_mfma<<<dim3(TT / 64, BB * 8), dim3(256), 0, stream>>>(qkv_b, yb);
    gemm_bt64<2><<<dim3(8, 48, 2), dim3(256), 0, stream>>>(
        yb, pw_b + (size_t)l * DDIM * DDIM, pb + (size_t)l * DDIM, tmp_b, DDIM, DDIM);
    add_ln<2><<<dim3(MM / 4), dim3(256), 0, stream>>>(
        xb, tmp_b, l1w + (size_t)l * DDIM, l1b + (size_t)l * DDIM, xb);
    gemm97<1, 1, 1, 0><<<dim3(16, 24), dim3(256), 0, stream>>>(
        xb, fw_b + (size_t)l * FF * DDIM, fb + (size_t)l * FF, hb, FF, DDIM);
    gemm_bt64<2><<<dim3(8, 48, 2), dim3(256), 0, stream>>>(
        hb, f2w_b + (size_t)l * DDIM * FF, f2bi + (size_t)l * DDIM, tmp_b, DDIM, FF);
    add_ln<2><<<dim3(MM / 4), dim3(256), 0, stream>>>(
        xb, tmp_b, l2w + (size_t)l * DDIM, l2b + (size_t)l * DDIM, xb);
  }
  add_ln<0><<<dim3(MM / 4), dim3(256), 0, stream>>>(xb, nullptr, lnfw, lnfb, xb);

  gemm97<0, 0, 0, 1><<<dim3((VV / 128) * 24), dim3(256), 0, stream>>>(
      xb, wte_b, nullptr, (float*)d_out, VV, DDIM);
}

// Round 9
// 879.586 us; speedup vs baseline: 1.0679x; 1.0679x over previous
//
#include <hip/hip_runtime.h>
#include <hip/hip_bf16.h>

#define AS1 __attribute__((address_space(1)))
#define AS3 __attribute__((address_space(3)))

typedef __attribute__((ext_vector_type(8))) short short8;
typedef __attribute__((ext_vector_type(4))) float f32x4;

constexpr int BB = 4, TT = 768, DDIM = 512, LL = 6, VV = 50304, FF = 2048;
constexpr int MM = BB * TT;  // 3072 rows of the activation matrix

// ---------- helpers ----------
__device__ inline unsigned short f2b(float f) {
  union { float f; unsigned u; } a; a.f = f;
  unsigned u = a.u;
  return (unsigned short)((u + 0x7FFFu + ((u >> 16) & 1u)) >> 16);  // RNE
}
__device__ inline float b2f(unsigned short u) {
  union { unsigned u; float f; } a; a.u = ((unsigned)u) << 16; return a.f;
}

// ---------- fused f32 -> bf16 convert of all 5 weight tensors ----------
constexpr size_t CW0 = (size_t)VV * DDIM;                  // wte
constexpr size_t CW1 = CW0 + (size_t)LL * 3 * DDIM * DDIM; // + c_attn_w
constexpr size_t CW2 = CW1 + (size_t)LL * DDIM * DDIM;     // + c_proj_w
constexpr size_t CW3 = CW2 + (size_t)LL * FF * DDIM;       // + fc_w
constexpr size_t CW4 = CW3 + (size_t)LL * DDIM * FF;       // + fc2_w

__global__ void cvt_all(const float* __restrict__ wte, const float* __restrict__ aw,
                        const float* __restrict__ pw, const float* __restrict__ fw,
                        const float* __restrict__ f2w, ushort* __restrict__ out) {
  size_t i = ((size_t)blockIdx.x * 256 + threadIdx.x) * 4;
  if (i >= CW4) return;
  const float* src; size_t base;
  if (i < CW0)      { src = wte; base = 0; }
  else if (i < CW1) { src = aw;  base = CW0; }
  else if (i < CW2) { src = pw;  base = CW1; }
  else if (i < CW3) { src = fw;  base = CW2; }
  else              { src = f2w; base = CW3; }
  float4 v = *(const float4*)(src + (i - base));
  ushort4 o = { f2b(v.x), f2b(v.y), f2b(v.z), f2b(v.w) };
  *(ushort4*)(out + i) = o;
}

// ---------- embedding: x = wte[idx] + wpe[t] ----------
__global__ void embed_kernel(const int* __restrict__ idx, const float* __restrict__ wte,
                             const float* __restrict__ wpe, float* __restrict__ x,
                             ushort* __restrict__ xb) {
  int row = blockIdx.x;
  int t = row % TT;
  int tok = idx[row];
  int c = threadIdx.x * 4;
  float4 a = *(const float4*)(wte + (size_t)tok * DDIM + c);
  float4 p = *(const float4*)(wpe + (size_t)t * DDIM + c);
  a.x += p.x; a.y += p.y; a.z += p.z; a.w += p.w;
  *(float4*)(x + (size_t)row * DDIM + c) = a;
  ushort4 o = { f2b(a.x), f2b(a.y), f2b(a.z), f2b(a.w) };
  *(ushort4*)(xb + (size_t)row * DDIM + c) = o;
}

// ---------- layer GEMM (qkv/fc): BK=64, swizzled LDS, dbuf 2-phase ----------
// C[M,N] = A[M,K] * Bw[N,K]^T + bias; bf16 out; optional relu.
// NT=512: 8 waves (4x2, wave tile 32x32).
template <int RELU, int NT>
__global__ __launch_bounds__(NT) void gemm_bt64(
    const ushort* __restrict__ A, const ushort* __restrict__ Bw,
    const float* __restrict__ bias, ushort* __restrict__ Cv, int Ndim, int K) {
  constexpr int BM = 128, BN = 64;
  constexpr int WROWS = (NT == 512) ? 4 : 2;
  constexpr int WTM = BM / WROWS, WTN = BN / 2;
  constexpr int MI = WTM / 16, NJ = WTN / 16;
  constexpr int RPI = NT / 8;
  __shared__ ushort sA[2][BM * 64];
  __shared__ ushort sB[2][BN * 64];
  const int tid = threadIdx.x;
  const int wid = tid >> 6, lane = tid & 63;
  const int m0 = blockIdx.y * BM, n0 = blockIdx.x * BN;
  const int wm = (wid >> 1) * WTM, wn = (wid & 1) * WTN;

  f32x4 zero = {0.f, 0.f, 0.f, 0.f};
  f32x4 acc[MI][NJ];
#pragma unroll
  for (int i = 0; i < MI; i++)
#pragma unroll
    for (int j = 0; j < NJ; j++) acc[i][j] = zero;

  const int r = tid >> 3;
  const int cg = ((tid & 7) ^ (r & 7)) * 8;
  const ushort* gA = A + (size_t)(m0 + r) * K + cg;
  const ushort* gB = Bw + (size_t)(n0 + r) * K + cg;

  auto stage = [&](int buf, int kk) {
    const ushort* a0 = gA + kk * 64;
    const ushort* b0 = gB + kk * 64;
    ushort* dA = &sA[buf][0] + wid * 512;
    ushort* dB = &sB[buf][0] + wid * 512;
#pragma unroll
    for (int p = 0; p < BM / RPI; p++)
      __builtin_amdgcn_global_load_lds((const AS1 void*)(a0 + (size_t)p * RPI * K),
                                       (AS3 void*)(dA + p * RPI * 64), 16, 0, 0);
#pragma unroll
    for (int p = 0; p < BN / RPI; p++)
      __builtin_amdgcn_global_load_lds((const AS1 void*)(b0 + (size_t)p * RPI * K),
                                       (AS3 void*)(dB + p * RPI * 64), 16, 0, 0);
  };

  const int fr = lane & 15;
  const int fk = (lane >> 4) * 8;
  auto ldfrag = [&](const ushort* s, int rowbase, int sub) -> short8 {
    const int row = rowbase + fr;
    const int off = row * 128 + ((sub * 64 + fk * 2) ^ ((fr & 7) << 4));
    return *(const short8*)((const char*)s + off);
  };

  const int nK = K >> 6;
  stage(0, 0);
  __syncthreads();
  int buf = 0;
  for (int kk = 0; kk < nK; ++kk) {
    if (kk + 1 < nK) stage(buf ^ 1, kk + 1);
    short8 af[MI][2], bf[NJ][2];
#pragma unroll
    for (int i = 0; i < MI; i++)
#pragma unroll
      for (int s = 0; s < 2; s++) af[i][s] = ldfrag(&sA[buf][0], wm + i * 16, s);
#pragma unroll
    for (int j = 0; j < NJ; j++)
#pragma unroll
      for (int s = 0; s < 2; s++) bf[j][s] = ldfrag(&sB[buf][0], wn + j * 16, s);
#pragma unroll
    for (int i = 0; i < MI; i++)
#pragma unroll
      for (int j = 0; j < NJ; j++)
#pragma unroll
        for (int s = 0; s < 2; s++)
          acc[i][j] = __builtin_amdgcn_mfma_f32_16x16x32_bf16(af[i][s], bf[j][s], acc[i][j], 0, 0, 0);
    __syncthreads();
    buf ^= 1;
  }

  const int cr = (lane >> 4) * 4;
  const int cc = lane & 15;
#pragma unroll
  for (int j = 0; j < NJ; j++) {
    const int gcol = n0 + wn + j * 16 + cc;
    const float bv = bias[gcol];
#pragma unroll
    for (int i = 0; i < MI; i++) {
      const int grow = m0 + wm + i * 16 + cr;
#pragma unroll
      for (int rr = 0; rr < 4; ++rr) {
        float v = acc[i][j][rr] + bv;
        if (RELU) v = fmaxf(v, 0.0f);
        Cv[(size_t)(grow + rr) * Ndim + gcol] = f2b(v);
      }
    }
  }
}

// ---------- proj/fc2 GEMM: m97 128x128 BK=32 inner loop + split-K planes ------
// 32KB LDS, 16 MFMA : 8 ds_read per wave-K-step (2:1). bf16 partial planes,
// bias added by plane z==0 only.
template <int SPLITK>
__global__ __launch_bounds__(256) void gemm97sk(
    const ushort* __restrict__ A, const ushort* __restrict__ Bw,
    const float* __restrict__ bias, ushort* __restrict__ Cv, int Ndim, int K) {
  __shared__ ushort sA[2][128 * 32];
  __shared__ ushort sB[2][128 * 32];
  const int tid = threadIdx.x;
  const int wid = tid >> 6, lane = tid & 63;
  const int m0 = blockIdx.y * 128, n0 = blockIdx.x * 128;
  const int kchunk = K / SPLITK;
  const int ks0 = blockIdx.z * kchunk;
  const int wm = (wid >> 1) * 64, wn = (wid & 1) * 64;

  f32x4 zero = {0.f, 0.f, 0.f, 0.f};
  f32x4 acc[4][4];
#pragma unroll
  for (int i = 0; i < 4; i++)
#pragma unroll
    for (int j = 0; j < 4; j++) acc[i][j] = zero;

  const int r4 = tid >> 2;
  const int c8 = (tid & 3) * 8;
  const ushort* gA = A + (size_t)(m0 + r4) * K + ks0 + c8;
  const ushort* gB = Bw + (size_t)(n0 + r4) * K + ks0 + c8;
  const size_t K64 = (size_t)64 * K;

  auto stage = [&](int buf, int kk) {
    const ushort* a0 = gA + kk * 32;
    const ushort* b0 = gB + kk * 32;
    ushort* dA = &sA[buf][0] + wid * 512;
    ushort* dB = &sB[buf][0] + wid * 512;
#pragma unroll
    for (int i = 0; i < 2; i++)
      __builtin_amdgcn_global_load_lds((const AS1 void*)(a0 + (size_t)i * K64),
                                       (AS3 void*)(dA + i * 2048), 16, 0, 0);
#pragma unroll
    for (int i = 0; i < 2; i++)
      __builtin_amdgcn_global_load_lds((const AS1 void*)(b0 + (size_t)i * K64),
                                       (AS3 void*)(dB + i * 2048), 16, 0, 0);
  };

  const int fr = lane & 15;
  const int fk = (lane >> 4) * 8;
  const int nK = kchunk >> 5;
  stage(0, 0);
  __syncthreads();
  int buf = 0;
  for (int kk = 0; kk < nK; ++kk) {
    if (kk + 1 < nK) stage(buf ^ 1, kk + 1);
    const ushort* pa0 = &sA[buf][0] + (wm + fr) * 32 + fk;
    const ushort* pb0 = &sB[buf][0] + (wn + fr) * 32 + fk;
    short8 af[4], bf[4];
#pragma unroll
    for (int i = 0; i < 4; i++) af[i] = *(const short8*)(pa0 + i * 16 * 32);
#pragma unroll
    for (int j = 0; j < 4; j++) bf[j] = *(const short8*)(pb0 + j * 16 * 32);
#pragma unroll
    for (int i = 0; i < 4; i++)
#pragma unroll
      for (int j = 0; j < 4; j++)
        acc[i][j] = __builtin_amdgcn_mfma_f32_16x16x32_bf16(af[i], bf[j], acc[i][j], 0, 0, 0);
    __syncthreads();
    buf ^= 1;
  }

  const int cr = (lane >> 4) * 4;
  const int cc = lane & 15;
  ushort* Cb = Cv + (size_t)blockIdx.z * MM * Ndim;
#pragma unroll
  for (int j = 0; j < 4; j++) {
    const int gcol = n0 + wn + j * 16 + cc;
    const float bv = (blockIdx.z == 0) ? bias[gcol] : 0.0f;
#pragma unroll
    for (int i = 0; i < 4; i++) {
      const int grow = m0 + wm + i * 16 + cr;
#pragma unroll
      for (int rr = 0; rr < 4; ++rr)
        Cb[(size_t)(grow + rr) * Ndim + gcol] = f2b(acc[i][j][rr] + bv);
    }
  }
}

// ---------- head GEMM (BK=32, 128x128, XCD-swizzled, dbuf 2-phase) ----------
__global__ __launch_bounds__(256) void gemm_head(
    const ushort* __restrict__ A, const ushort* __restrict__ Bw,
    float* __restrict__ Cv, int Ndim, int K) {
  __shared__ ushort sA[2][128 * 32];
  __shared__ ushort sB[2][128 * 32];
  const int tid = threadIdx.x;
  const int wid = tid >> 6, lane = tid & 63;
  int id = blockIdx.x;
  int v = (id >> 3) + (id & 7) * ((int)gridDim.x >> 3);
  const int m0 = (v % 24) * 128;       // same-B blocks consecutive per XCD
  const int n0 = (v / 24) * 128;
  const int wm = (wid >> 1) * 64, wn = (wid & 1) * 64;

  f32x4 zero = {0.f, 0.f, 0.f, 0.f};
  f32x4 acc[4][4];
#pragma unroll
  for (int i = 0; i < 4; i++)
#pragma unroll
    for (int j = 0; j < 4; j++) acc[i][j] = zero;

  const int r4 = tid >> 2;
  const int c8 = (tid & 3) * 8;
  const ushort* gA = A + (size_t)(m0 + r4) * K + c8;
  const ushort* gB = Bw + (size_t)(n0 + r4) * K + c8;
  const size_t K64 = (size_t)64 * K;

  auto stage = [&](int buf, int kk) {
    const ushort* a0 = gA + kk * 32;
    const ushort* b0 = gB + kk * 32;
    ushort* dA = &sA[buf][0] + wid * 512;
    ushort* dB = &sB[buf][0] + wid * 512;
#pragma unroll
    for (int i = 0; i < 2; i++)
      __builtin_amdgcn_global_load_lds((const AS1 void*)(a0 + (size_t)i * K64),
                                       (AS3 void*)(dA + i * 2048), 16, 0, 0);
#pragma unroll
    for (int i = 0; i < 2; i++)
      __builtin_amdgcn_global_load_lds((const AS1 void*)(b0 + (size_t)i * K64),
                                       (AS3 void*)(dB + i * 2048), 16, 0, 0);
  };

  const int fr = lane & 15;
  const int fk = (lane >> 4) * 8;
  const int nK = K >> 5;
  stage(0, 0);
  __syncthreads();
  int buf = 0;
  for (int kk = 0; kk < nK; ++kk) {
    if (kk + 1 < nK) stage(buf ^ 1, kk + 1);
    const ushort* pa0 = &sA[buf][0] + (wm + fr) * 32 + fk;
    const ushort* pb0 = &sB[buf][0] + (wn + fr) * 32 + fk;
    short8 af[4], bf[4];
#pragma unroll
    for (int i = 0; i < 4; i++) af[i] = *(const short8*)(pa0 + i * 16 * 32);
#pragma unroll
    for (int j = 0; j < 4; j++) bf[j] = *(const short8*)(pb0 + j * 16 * 32);
#pragma unroll
    for (int i = 0; i < 4; i++)
#pragma unroll
      for (int j = 0; j < 4; j++)
        acc[i][j] = __builtin_amdgcn_mfma_f32_16x16x32_bf16(af[i], bf[j], acc[i][j], 0, 0, 0);
    __syncthreads();
    buf ^= 1;
  }

  const int cr = (lane >> 4) * 4;
  const int cc = lane & 15;
#pragma unroll
  for (int j = 0; j < 4; j++) {
    const int gcol = n0 + wn + j * 16 + cc;
#pragma unroll
    for (int i = 0; i < 4; i++) {
      const int grow = m0 + wm + i * 16 + cr;
#pragma unroll
      for (int rr = 0; rr < 4; ++rr)
        Cv[(size_t)(grow + rr) * Ndim + gcol] = acc[i][j][rr];
    }
  }
}

// ---------- MFMA fused causal attention ----------
__device__ inline short8 lds_swz_read(const ushort* base, int row, int elem) {
  return *(const short8*)((const char*)base + row * 128 + ((elem * 2) ^ ((row & 7) << 4)));
}

__global__ __launch_bounds__(256) void attn_mfma(const ushort* __restrict__ qkv,
                                                 ushort* __restrict__ yb) {
  __shared__ ushort sK[64 * 64];
  __shared__ ushort sVT[64 * 64];
  __shared__ ushort sP[4 * 16 * 64];
  const int tid = threadIdx.x;
  const int wid = tid >> 6, lane = tid & 63;
  const int qt = blockIdx.x;
  const int b = blockIdx.y >> 3, h = blockIdx.y & 7;
  const int q0 = qt * 64;
  const int qw = q0 + wid * 16;

  const int fr = lane & 15;
  const int fk = (lane >> 4) * 8;
  ushort* sPw = sP + wid * 16 * 64;

  short8 qf[2];
  {
    const ushort* qp = qkv + (size_t)(b * TT + qw + fr) * 1536 + h * 64;
    qf[0] = *(const short8*)(qp + fk);
    qf[1] = *(const short8*)(qp + 32 + fk);
  }

  const int r4 = tid >> 2;
  const int c32 = (tid & 3) * 16;

  f32x4 zero = {0.f, 0.f, 0.f, 0.f};
  f32x4 acc[4] = {zero, zero, zero, zero};
  float mrow[4] = {-INFINITY, -INFINITY, -INFINITY, -INFINITY};
  float lrow[4] = {0.f, 0.f, 0.f, 0.f};

  for (int kt = 0; kt <= qt; ++kt) {
    __syncthreads();
    const int k0 = kt * 64;
    {
      const ushort* kp = qkv + (size_t)(b * TT + k0 + r4) * 1536 + 512 + h * 64 + c32;
      short8 kv0 = *(const short8*)kp;
      short8 kv1 = *(const short8*)(kp + 8);
      char* skb = (char*)sK + r4 * 128;
      *(short8*)(skb + ((c32 * 2) ^ ((r4 & 7) << 4))) = kv0;
      *(short8*)(skb + ((c32 * 2 + 16) ^ ((r4 & 7) << 4))) = kv1;
      const ushort* vp = kp + 512;
      short8 vv0 = *(const short8*)vp;
      short8 vv1 = *(const short8*)(vp + 8);
#pragma unroll
      for (int i = 0; i < 8; i++) {
        int d0 = c32 + i, d1 = c32 + 8 + i;
        *(ushort*)((char*)sVT + d0 * 128 + ((r4 * 2) ^ ((d0 & 7) << 4))) = (ushort)vv0[i];
        *(ushort*)((char*)sVT + d1 * 128 + ((r4 * 2) ^ ((d1 & 7) << 4))) = (ushort)vv1[i];
      }
    }
    __syncthreads();

    f32x4 sfr[4];
#pragma unroll
    for (int j = 0; j < 4; j++) {
      short8 kb0 = lds_swz_read(sK, j * 16 + fr, fk);
      short8 kb1 = lds_swz_read(sK, j * 16 + fr, 32 + fk);
      f32x4 s = __builtin_amdgcn_mfma_f32_16x16x32_bf16(qf[0], kb0, zero, 0, 0, 0);
      s = __builtin_amdgcn_mfma_f32_16x16x32_bf16(qf[1], kb1, s, 0, 0, 0);
      sfr[j] = s * 0.125f;
    }
    if (kt == qt) {
#pragma unroll
      for (int j = 0; j < 4; j++)
#pragma unroll
        for (int rr = 0; rr < 4; ++rr)
          if (j * 16 + fr > wid * 16 + (lane >> 4) * 4 + rr) sfr[j][rr] = -INFINITY;
    }

    float scl[4];
#pragma unroll
    for (int rr = 0; rr < 4; ++rr) {
      float t = fmaxf(fmaxf(sfr[0][rr], sfr[1][rr]), fmaxf(sfr[2][rr], sfr[3][rr]));
      t = fmaxf(t, __shfl_xor(t, 1));
      t = fmaxf(t, __shfl_xor(t, 2));
      t = fmaxf(t, __shfl_xor(t, 4));
      t = fmaxf(t, __shfl_xor(t, 8));
      const float mnew = fmaxf(mrow[rr], t);
      scl[rr] = __expf(mrow[rr] - mnew);
      mrow[rr] = mnew;
      float ps = 0.f;
#pragma unroll
      for (int j = 0; j < 4; j++) {
        float p = __expf(sfr[j][rr] - mnew);
        sfr[j][rr] = p;
        ps += p;
      }
      ps += __shfl_xor(ps, 1);
      ps += __shfl_xor(ps, 2);
      ps += __shfl_xor(ps, 4);
      ps += __shfl_xor(ps, 8);
      lrow[rr] = lrow[rr] * scl[rr] + ps;
    }

#pragma unroll
    for (int j = 0; j < 4; j++)
#pragma unroll
      for (int rr = 0; rr < 4; ++rr) {
        int q = (lane >> 4) * 4 + rr, k = j * 16 + fr;
        *(ushort*)((char*)sPw + q * 128 + ((k * 2) ^ ((q & 7) << 4))) = f2b(sfr[j][rr]);
      }

#pragma unroll
    for (int f = 0; f < 4; f++)
#pragma unroll
      for (int rr = 0; rr < 4; ++rr) acc[f][rr] *= scl[rr];

    short8 pa0 = lds_swz_read(sPw, fr, fk);
    short8 pa1 = lds_swz_read(sPw, fr, 32 + fk);
#pragma unroll
    for (int f = 0; f < 4; f++) {
      short8 vb0 = lds_swz_read(sVT, f * 16 + fr, fk);
      short8 vb1 = lds_swz_read(sVT, f * 16 + fr, 32 + fk);
      acc[f] = __builtin_amdgcn_mfma_f32_16x16x32_bf16(pa0, vb0, acc[f], 0, 0, 0);
      acc[f] = __builtin_amdgcn_mfma_f32_16x16x32_bf16(pa1, vb1, acc[f], 0, 0, 0);
    }
  }

#pragma unroll
  for (int rr = 0; rr < 4; ++rr) {
    const float inv = 1.0f / lrow[rr];
    const int token = b * TT + qw + (lane >> 4) * 4 + rr;
    ushort* yp = yb + (size_t)token * DDIM + h * 64 + fr;
#pragma unroll
    for (int f = 0; f < 4; f++) yp[f * 16] = f2b(acc[f][rr] * inv);
  }
}

// ---------- fused residual add (+ S bf16 split-K planes) + LayerNorm ----------
template <int S>
__global__ __launch_bounds__(256) void add_ln(const float* __restrict__ x,
                                              const ushort* __restrict__ y,
                                              const float* __restrict__ w,
                                              const float* __restrict__ bb,
                                              float* __restrict__ xo,
                                              ushort* __restrict__ xb) {
  const int row = blockIdx.x * 4 + (threadIdx.x >> 6);
  const int lane = threadIdx.x & 63;
  const size_t base = (size_t)row * DDIM + lane * 8;
  f32x4 a0 = *(const f32x4*)(x + base);
  f32x4 a1 = *(const f32x4*)(x + base + 4);
#pragma unroll
  for (int s = 0; s < S; ++s) {
    short8 v = *(const short8*)(y + (size_t)s * MM * DDIM + base);
    f32x4 p0 = { b2f((unsigned short)v[0]), b2f((unsigned short)v[1]),
                 b2f((unsigned short)v[2]), b2f((unsigned short)v[3]) };
    f32x4 p1 = { b2f((unsigned short)v[4]), b2f((unsigned short)v[5]),
                 b2f((unsigned short)v[6]), b2f((unsigned short)v[7]) };
    a0 += p0; a1 += p1;
  }
  float sm = (a0[0] + a0[1] + a0[2] + a0[3]) + (a1[0] + a1[1] + a1[2] + a1[3]);
  f32x4 q0 = a0 * a0, q1 = a1 * a1;
  float ss = (q0[0] + q0[1] + q0[2] + q0[3]) + (q1[0] + q1[1] + q1[2] + q1[3]);
#pragma unroll
  for (int o = 1; o < 64; o <<= 1) {
    sm += __shfl_xor(sm, o);
    ss += __shfl_xor(ss, o);
  }
  const float mu = sm * (1.0f / DDIM);
  const float var = ss * (1.0f / DDIM) - mu * mu;
  const float rs = rsqrtf(var + 1e-5f);
  const int c = lane * 8;
  f32x4 w0 = *(const f32x4*)(w + c), w1 = *(const f32x4*)(w + c + 4);
  f32x4 b0 = *(const f32x4*)(bb + c), b1 = *(const f32x4*)(bb + c + 4);
  f32x4 o0 = (a0 - mu) * rs * w0 + b0;
  f32x4 o1 = (a1 - mu) * rs * w1 + b1;
  *(f32x4*)(xo + base) = o0;
  *(f32x4*)(xo + base + 4) = o1;
  ushort4 u0 = { f2b(o0[0]), f2b(o0[1]), f2b(o0[2]), f2b(o0[3]) };
  ushort4 u1 = { f2b(o1[0]), f2b(o1[1]), f2b(o1[2]), f2b(o1[3]) };
  *(ushort4*)(xb + base) = u0;
  *(ushort4*)(xb + base + 4) = u1;
}

// ---------- launch ----------
extern "C" void kernel_launch(void* const* d_in, const int* in_sizes, int n_in,
                              void* d_out, int out_size, void* d_ws, size_t ws_size,
                              hipStream_t stream) {
  const int*   idx  = (const int*)d_in[0];
  const float* wte  = (const float*)d_in[1];
  const float* wpe  = (const float*)d_in[2];
  const float* aw   = (const float*)d_in[3];
  const float* ab   = (const float*)d_in[4];
  const float* pw   = (const float*)d_in[5];
  const float* pb   = (const float*)d_in[6];
  const float* fw   = (const float*)d_in[7];
  const float* fb   = (const float*)d_in[8];
  const float* f2w  = (const float*)d_in[9];
  const float* f2bi = (const float*)d_in[10];
  const float* l1w  = (const float*)d_in[11];
  const float* l1b  = (const float*)d_in[12];
  const float* l2w  = (const float*)d_in[13];
  const float* l2b  = (const float*)d_in[14];
  const float* lnfw = (const float*)d_in[15];
  const float* lnfb = (const float*)d_in[16];

  char* ws = (char*)d_ws;
  size_t off = 0;
  auto take = [&](size_t bytes) -> void* {
    void* p = ws + off;
    off += (bytes + 255) & ~(size_t)255;
    return p;
  };
  ushort* wte_b = (ushort*)take((size_t)VV * DDIM * 2);
  ushort* aw_b  = (ushort*)take((size_t)LL * 3 * DDIM * DDIM * 2);
  ushort* pw_b  = (ushort*)take((size_t)LL * DDIM * DDIM * 2);
  ushort* fw_b  = (ushort*)take((size_t)LL * FF * DDIM * 2);
  ushort* f2w_b = (ushort*)take((size_t)LL * DDIM * FF * 2);
  float*  x     = (float*)take((size_t)MM * DDIM * 4);
  ushort* xb    = (ushort*)take((size_t)MM * DDIM * 2);
  ushort* qkv_b = (ushort*)take((size_t)MM * 3 * DDIM * 2);
  ushort* yb    = (ushort*)take((size_t)MM * DDIM * 2);
  ushort* tmp_b = (ushort*)take((size_t)4 * MM * DDIM * 2);  // 4 bf16 split-K planes
  ushort* hb    = (ushort*)take((size_t)MM * FF * 2);

  cvt_all<<<dim3((unsigned)(CW4 / 4 / 256)), dim3(256), 0, stream>>>(
      wte, aw, pw, fw, f2w, wte_b);

  embed_kernel<<<dim3(MM), dim3(128), 0, stream>>>(idx, wte, wpe, x, xb);

  for (int l = 0; l < LL; ++l) {
    gemm_bt64<0, 512><<<dim3(24, 24), dim3(512), 0, stream>>>(
        xb, aw_b + (size_t)l * 3 * DDIM * DDIM, ab + (size_t)l * 3 * DDIM, qkv_b, 3 * DDIM, DDIM);
    attn_mfma<<<dim3(TT / 64, BB * 8), dim3(256), 0, stream>>>(qkv_b, yb);
    gemm97sk<4><<<dim3(4, 24, 4), dim3(256), 0, stream>>>(
        yb, pw_b + (size_t)l * DDIM * DDIM, pb + (size_t)l * DDIM, tmp_b, DDIM, DDIM);
    add_ln<4><<<dim3(MM / 4), dim3(256), 0, stream>>>(
        x, tmp_b, l1w + (size_t)l * DDIM, l1b + (size_t)l * DDIM, x, xb);
    gemm_bt64<1, 512><<<dim3(32, 24), dim3(512), 0, stream>>>(
        xb, fw_b + (size_t)l * FF * DDIM, fb + (size_t)l * FF, hb, FF, DDIM);
    gemm97sk<4><<<dim3(4, 24, 4), dim3(256), 0, stream>>>(
        hb, f2w_b + (size_t)l * DDIM * FF, f2bi + (size_t)l * DDIM, tmp_b, DDIM, FF);
    add_ln<4><<<dim3(MM / 4), dim3(256), 0, stream>>>(
        x, tmp_b, l2w + (size_t)l * DDIM, l2b + (size_t)l * DDIM, x, xb);
  }
  add_ln<0><<<dim3(MM / 4), dim3(256), 0, stream>>>(x, nullptr, lnfw, lnfb, x, xb);

  gemm_head<<<dim3((VV / 128) * 24), dim3(256), 0, stream>>>(
      xb, wte_b, (float*)d_out, VV, DDIM);
}

// Round 10
// 855.578 us; speedup vs baseline: 1.0979x; 1.0281x over previous
//
#include <hip/hip_runtime.h>
#include <hip/hip_bf16.h>

#define AS1 __attribute__((address_space(1)))
#define AS3 __attribute__((address_space(3)))

typedef __attribute__((ext_vector_type(8))) short short8;
typedef __attribute__((ext_vector_type(4))) float f32x4;

constexpr int BB = 4, TT = 768, DDIM = 512, LL = 6, VV = 50304, FF = 2048;
constexpr int MM = BB * TT;  // 3072 rows of the activation matrix

// ---------- helpers ----------
__device__ inline unsigned short f2b(float f) {
  union { float f; unsigned u; } a; a.f = f;
  unsigned u = a.u;
  return (unsigned short)((u + 0x7FFFu + ((u >> 16) & 1u)) >> 16);  // RNE
}
__device__ inline float b2f(unsigned short u) {
  union { unsigned u; float f; } a; a.u = ((unsigned)u) << 16; return a.f;
}

// ---------- fused f32 -> bf16 convert of all 5 weight tensors ----------
constexpr size_t CW0 = (size_t)VV * DDIM;                  // wte
constexpr size_t CW1 = CW0 + (size_t)LL * 3 * DDIM * DDIM; // + c_attn_w
constexpr size_t CW2 = CW1 + (size_t)LL * DDIM * DDIM;     // + c_proj_w
constexpr size_t CW3 = CW2 + (size_t)LL * FF * DDIM;       // + fc_w
constexpr size_t CW4 = CW3 + (size_t)LL * DDIM * FF;       // + fc2_w

__global__ void cvt_all(const float* __restrict__ wte, const float* __restrict__ aw,
                        const float* __restrict__ pw, const float* __restrict__ fw,
                        const float* __restrict__ f2w, ushort* __restrict__ out) {
  size_t i = ((size_t)blockIdx.x * 256 + threadIdx.x) * 4;
  if (i >= CW4) return;
  const float* src; size_t base;
  if (i < CW0)      { src = wte; base = 0; }
  else if (i < CW1) { src = aw;  base = CW0; }
  else if (i < CW2) { src = pw;  base = CW1; }
  else if (i < CW3) { src = fw;  base = CW2; }
  else              { src = f2w; base = CW3; }
  float4 v = *(const float4*)(src + (i - base));
  ushort4 o = { f2b(v.x), f2b(v.y), f2b(v.z), f2b(v.w) };
  *(ushort4*)(out + i) = o;
}

// ---------- embedding: x = wte[idx] + wpe[t] ----------
__global__ void embed_kernel(const int* __restrict__ idx, const float* __restrict__ wte,
                             const float* __restrict__ wpe, float* __restrict__ x,
                             ushort* __restrict__ xb) {
  int row = blockIdx.x;
  int t = row % TT;
  int tok = idx[row];
  int c = threadIdx.x * 4;
  float4 a = *(const float4*)(wte + (size_t)tok * DDIM + c);
  float4 p = *(const float4*)(wpe + (size_t)t * DDIM + c);
  a.x += p.x; a.y += p.y; a.z += p.z; a.w += p.w;
  *(float4*)(x + (size_t)row * DDIM + c) = a;
  ushort4 o = { f2b(a.x), f2b(a.y), f2b(a.z), f2b(a.w) };
  *(ushort4*)(xb + (size_t)row * DDIM + c) = o;
}

// ---------- layer GEMM: BK=64, swizzled LDS, dbuf 2-phase, optional split-K ----
// C[M,N] (or partial plane z) = A[M,K-chunk] * Bw[N,K-chunk]^T (+ bias on z==0)
// LDS layout: row-major [row][64 bf16 = 128B], byte swizzle: slot ^= (row&7).
// global_load_lds writes linearly (lane*16B) so the GLOBAL source chunk is
// inverse-swizzled per-lane (rule #21: both-sides-or-neither).
template <int RELU, int OUTBF16, int BM, int BN, int SPLITK, int NT>
__global__ __launch_bounds__(NT) void gemm_bt64(
    const ushort* __restrict__ A, const ushort* __restrict__ Bw,
    const float* __restrict__ bias, void* __restrict__ Cv, int Ndim, int K) {
  constexpr int WROWS = (NT == 512) ? 4 : 2;
  constexpr int WTM = BM / WROWS, WTN = BN / 2;
  constexpr int MI = WTM / 16, NJ = WTN / 16;
  constexpr int RPI = NT / 8;                   // rows per gload_lds instruction
  __shared__ ushort sA[2][BM * 64];
  __shared__ ushort sB[2][BN * 64];
  const int tid = threadIdx.x;
  const int wid = tid >> 6, lane = tid & 63;
  const int m0 = blockIdx.y * BM, n0 = blockIdx.x * BN;
  const int kchunk = K / SPLITK;
  const int ks0 = (SPLITK > 1) ? blockIdx.z * kchunk : 0;
  const int wm = (wid >> 1) * WTM, wn = (wid & 1) * WTN;

  f32x4 zero = {0.f, 0.f, 0.f, 0.f};
  f32x4 acc[MI][NJ];
#pragma unroll
  for (int i = 0; i < MI; i++)
#pragma unroll
    for (int j = 0; j < NJ; j++) acc[i][j] = zero;

  const int r = tid >> 3;
  const int cg = ((tid & 7) ^ (r & 7)) * 8;
  const ushort* gA = A + (size_t)(m0 + r) * K + ks0 + cg;
  const ushort* gB = Bw + (size_t)(n0 + r) * K + ks0 + cg;

  auto stage = [&](int buf, int kk) {
    const ushort* a0 = gA + kk * 64;
    const ushort* b0 = gB + kk * 64;
    ushort* dA = &sA[buf][0] + wid * 512;   // wave-uniform base; HW adds lane*16B
    ushort* dB = &sB[buf][0] + wid * 512;
#pragma unroll
    for (int p = 0; p < BM / RPI; p++)
      __builtin_amdgcn_global_load_lds((const AS1 void*)(a0 + (size_t)p * RPI * K),
                                       (AS3 void*)(dA + p * RPI * 64), 16, 0, 0);
#pragma unroll
    for (int p = 0; p < BN / RPI; p++)
      __builtin_amdgcn_global_load_lds((const AS1 void*)(b0 + (size_t)p * RPI * K),
                                       (AS3 void*)(dB + p * RPI * 64), 16, 0, 0);
  };

  const int fr = lane & 15;
  const int fk = (lane >> 4) * 8;
  auto ldfrag = [&](const ushort* s, int rowbase, int sub) -> short8 {
    const int row = rowbase + fr;
    const int off = row * 128 + ((sub * 64 + fk * 2) ^ ((fr & 7) << 4));
    return *(const short8*)((const char*)s + off);
  };

  const int nK = kchunk >> 6;
  stage(0, 0);
  __syncthreads();
  int buf = 0;
  for (int kk = 0; kk < nK; ++kk) {
    if (kk + 1 < nK) stage(buf ^ 1, kk + 1);
    short8 af[MI][2], bf[NJ][2];
#pragma unroll
    for (int i = 0; i < MI; i++)
#pragma unroll
      for (int s = 0; s < 2; s++) af[i][s] = ldfrag(&sA[buf][0], wm + i * 16, s);
#pragma unroll
    for (int j = 0; j < NJ; j++)
#pragma unroll
      for (int s = 0; s < 2; s++) bf[j][s] = ldfrag(&sB[buf][0], wn + j * 16, s);
#pragma unroll
    for (int i = 0; i < MI; i++)
#pragma unroll
      for (int j = 0; j < NJ; j++)
#pragma unroll
        for (int s = 0; s < 2; s++)
          acc[i][j] = __builtin_amdgcn_mfma_f32_16x16x32_bf16(af[i][s], bf[j][s], acc[i][j], 0, 0, 0);
    __syncthreads();
    buf ^= 1;
  }

  const int cr = (lane >> 4) * 4;
  const int cc = lane & 15;
  const size_t zoff = (SPLITK > 1) ? (size_t)blockIdx.z * MM * Ndim : 0;
  ushort* Cb = (ushort*)Cv + zoff;
  float*  Cf = (float*)Cv + zoff;
#pragma unroll
  for (int j = 0; j < NJ; j++) {
    const int gcol = n0 + wn + j * 16 + cc;
    const float bv = (bias && (SPLITK == 1 || blockIdx.z == 0)) ? bias[gcol] : 0.0f;
#pragma unroll
    for (int i = 0; i < MI; i++) {
      const int grow = m0 + wm + i * 16 + cr;
#pragma unroll
      for (int rr = 0; rr < 4; ++rr) {
        float v = acc[i][j][rr] + bv;
        if (RELU) v = fmaxf(v, 0.0f);
        if (OUTBF16)
          Cb[(size_t)(grow + rr) * Ndim + gcol] = f2b(v);
        else
          Cf[(size_t)(grow + rr) * Ndim + gcol] = v;
      }
    }
  }
}

// ---------- head GEMM (BK=32, 128x128, XCD-swizzled, dbuf 2-phase) ----------
__global__ __launch_bounds__(256) void gemm_head(
    const ushort* __restrict__ A, const ushort* __restrict__ Bw,
    float* __restrict__ Cv, int Ndim, int K) {
  __shared__ ushort sA[2][128 * 32];
  __shared__ ushort sB[2][128 * 32];
  const int tid = threadIdx.x;
  const int wid = tid >> 6, lane = tid & 63;
  int id = blockIdx.x;
  int v = (id >> 3) + (id & 7) * ((int)gridDim.x >> 3);
  const int m0 = (v % 24) * 128;       // same-B blocks consecutive per XCD
  const int n0 = (v / 24) * 128;
  const int wm = (wid >> 1) * 64, wn = (wid & 1) * 64;

  f32x4 zero = {0.f, 0.f, 0.f, 0.f};
  f32x4 acc[4][4];
#pragma unroll
  for (int i = 0; i < 4; i++)
#pragma unroll
    for (int j = 0; j < 4; j++) acc[i][j] = zero;

  const int r4 = tid >> 2;
  const int c8 = (tid & 3) * 8;
  const ushort* gA = A + (size_t)(m0 + r4) * K + c8;
  const ushort* gB = Bw + (size_t)(n0 + r4) * K + c8;
  const size_t K64 = (size_t)64 * K;

  auto stage = [&](int buf, int kk) {
    const ushort* a0 = gA + kk * 32;
    const ushort* b0 = gB + kk * 32;
    ushort* dA = &sA[buf][0] + wid * 512;
    ushort* dB = &sB[buf][0] + wid * 512;
#pragma unroll
    for (int i = 0; i < 2; i++)
      __builtin_amdgcn_global_load_lds((const AS1 void*)(a0 + (size_t)i * K64),
                                       (AS3 void*)(dA + i * 2048), 16, 0, 0);
#pragma unroll
    for (int i = 0; i < 2; i++)
      __builtin_amdgcn_global_load_lds((const AS1 void*)(b0 + (size_t)i * K64),
                                       (AS3 void*)(dB + i * 2048), 16, 0, 0);
  };

  const int fr = lane & 15;
  const int fk = (lane >> 4) * 8;
  const int nK = K >> 5;
  stage(0, 0);
  __syncthreads();
  int buf = 0;
  for (int kk = 0; kk < nK; ++kk) {
    if (kk + 1 < nK) stage(buf ^ 1, kk + 1);
    const ushort* pa0 = &sA[buf][0] + (wm + fr) * 32 + fk;
    const ushort* pb0 = &sB[buf][0] + (wn + fr) * 32 + fk;
    short8 af[4], bf[4];
#pragma unroll
    for (int i = 0; i < 4; i++) af[i] = *(const short8*)(pa0 + i * 16 * 32);
#pragma unroll
    for (int j = 0; j < 4; j++) bf[j] = *(const short8*)(pb0 + j * 16 * 32);
#pragma unroll
    for (int i = 0; i < 4; i++)
#pragma unroll
      for (int j = 0; j < 4; j++)
        acc[i][j] = __builtin_amdgcn_mfma_f32_16x16x32_bf16(af[i], bf[j], acc[i][j], 0, 0, 0);
    __syncthreads();
    buf ^= 1;
  }

  const int cr = (lane >> 4) * 4;
  const int cc = lane & 15;
#pragma unroll
  for (int j = 0; j < 4; j++) {
    const int gcol = n0 + wn + j * 16 + cc;
#pragma unroll
    for (int i = 0; i < 4; i++) {
      const int grow = m0 + wm + i * 16 + cr;
#pragma unroll
      for (int rr = 0; rr < 4; ++rr)
        Cv[(size_t)(grow + rr) * Ndim + gcol] = acc[i][j][rr];
    }
  }
}

// ---------- MFMA fused causal attention ----------
__device__ inline short8 lds_swz_read(const ushort* base, int row, int elem) {
  return *(const short8*)((const char*)base + row * 128 + ((elem * 2) ^ ((row & 7) << 4)));
}

__global__ __launch_bounds__(256) void attn_mfma(const ushort* __restrict__ qkv,
                                                 ushort* __restrict__ yb) {
  __shared__ ushort sK[64 * 64];
  __shared__ ushort sVT[64 * 64];
  __shared__ ushort sP[4 * 16 * 64];
  const int tid = threadIdx.x;
  const int wid = tid >> 6, lane = tid & 63;
  const int qt = blockIdx.x;
  const int b = blockIdx.y >> 3, h = blockIdx.y & 7;
  const int q0 = qt * 64;
  const int qw = q0 + wid * 16;

  const int fr = lane & 15;
  const int fk = (lane >> 4) * 8;
  ushort* sPw = sP + wid * 16 * 64;

  short8 qf[2];
  {
    const ushort* qp = qkv + (size_t)(b * TT + qw + fr) * 1536 + h * 64;
    qf[0] = *(const short8*)(qp + fk);
    qf[1] = *(const short8*)(qp + 32 + fk);
  }

  const int r4 = tid >> 2;           // K staging: row, 16-elem slice
  const int c32 = (tid & 3) * 16;
  const int kb = (tid >> 4) * 4;     // V staging: 4 k-rows
  const int db = (tid & 15) * 4;     // 4 d-cols

  f32x4 zero = {0.f, 0.f, 0.f, 0.f};
  f32x4 acc[4] = {zero, zero, zero, zero};
  float mrow[4] = {-INFINITY, -INFINITY, -INFINITY, -INFINITY};
  float lrow[4] = {0.f, 0.f, 0.f, 0.f};

  for (int kt = 0; kt <= qt; ++kt) {
    __syncthreads();
    const int k0 = kt * 64;
    {  // K tile: swizzled b128 writes
      const ushort* kp = qkv + (size_t)(b * TT + k0 + r4) * 1536 + 512 + h * 64 + c32;
      short8 kv0 = *(const short8*)kp;
      short8 kv1 = *(const short8*)(kp + 8);
      char* skb = (char*)sK + r4 * 128;
      *(short8*)(skb + ((c32 * 2) ^ ((r4 & 7) << 4))) = kv0;
      *(short8*)(skb + ((c32 * 2 + 16) ^ ((r4 & 7) << 4))) = kv1;
      // V^T tile: 4x4 in-register transpose, 4x ds_write_b64 (verified in R8)
      const ushort* vp = qkv + (size_t)(b * TT + k0 + kb) * 1536 + 1024 + h * 64 + db;
      ushort4 L0 = *(const ushort4*)vp;
      ushort4 L1 = *(const ushort4*)(vp + 1536);
      ushort4 L2 = *(const ushort4*)(vp + 3072);
      ushort4 L3 = *(const ushort4*)(vp + 4608);
      ushort4 c0 = { L0.x, L1.x, L2.x, L3.x };
      ushort4 c1 = { L0.y, L1.y, L2.y, L3.y };
      ushort4 c2 = { L0.z, L1.z, L2.z, L3.z };
      ushort4 c3 = { L0.w, L1.w, L2.w, L3.w };
      *(ushort4*)((char*)sVT + (db + 0) * 128 + ((kb * 2) ^ (((db + 0) & 7) << 4))) = c0;
      *(ushort4*)((char*)sVT + (db + 1) * 128 + ((kb * 2) ^ (((db + 1) & 7) << 4))) = c1;
      *(ushort4*)((char*)sVT + (db + 2) * 128 + ((kb * 2) ^ (((db + 2) & 7) << 4))) = c2;
      *(ushort4*)((char*)sVT + (db + 3) * 128 + ((kb * 2) ^ (((db + 3) & 7) << 4))) = c3;
    }
    __syncthreads();

    f32x4 sfr[4];
#pragma unroll
    for (int j = 0; j < 4; j++) {
      short8 kb0 = lds_swz_read(sK, j * 16 + fr, fk);
      short8 kb1 = lds_swz_read(sK, j * 16 + fr, 32 + fk);
      f32x4 s = __builtin_amdgcn_mfma_f32_16x16x32_bf16(qf[0], kb0, zero, 0, 0, 0);
      s = __builtin_amdgcn_mfma_f32_16x16x32_bf16(qf[1], kb1, s, 0, 0, 0);
      sfr[j] = s * 0.125f;
    }
    if (kt == qt) {
#pragma unroll
      for (int j = 0; j < 4; j++)
#pragma unroll
        for (int rr = 0; rr < 4; ++rr)
          if (j * 16 + fr > wid * 16 + (lane >> 4) * 4 + rr) sfr[j][rr] = -INFINITY;
    }

    float scl[4];
#pragma unroll
    for (int rr = 0; rr < 4; ++rr) {
      float t = fmaxf(fmaxf(sfr[0][rr], sfr[1][rr]), fmaxf(sfr[2][rr], sfr[3][rr]));
      t = fmaxf(t, __shfl_xor(t, 1));
      t = fmaxf(t, __shfl_xor(t, 2));
      t = fmaxf(t, __shfl_xor(t, 4));
      t = fmaxf(t, __shfl_xor(t, 8));
      const float mnew = fmaxf(mrow[rr], t);
      scl[rr] = __expf(mrow[rr] - mnew);
      mrow[rr] = mnew;
      float ps = 0.f;
#pragma unroll
      for (int j = 0; j < 4; j++) {
        float p = __expf(sfr[j][rr] - mnew);
        sfr[j][rr] = p;
        ps += p;
      }
      ps += __shfl_xor(ps, 1);
      ps += __shfl_xor(ps, 2);
      ps += __shfl_xor(ps, 4);
      ps += __shfl_xor(ps, 8);
      lrow[rr] = lrow[rr] * scl[rr] + ps;
    }

#pragma unroll
    for (int j = 0; j < 4; j++)
#pragma unroll
      for (int rr = 0; rr < 4; ++rr) {
        int q = (lane >> 4) * 4 + rr, k = j * 16 + fr;
        *(ushort*)((char*)sPw + q * 128 + ((k * 2) ^ ((q & 7) << 4))) = f2b(sfr[j][rr]);
      }

#pragma unroll
    for (int f = 0; f < 4; f++)
#pragma unroll
      for (int rr = 0; rr < 4; ++rr) acc[f][rr] *= scl[rr];

    short8 pa0 = lds_swz_read(sPw, fr, fk);
    short8 pa1 = lds_swz_read(sPw, fr, 32 + fk);
#pragma unroll
    for (int f = 0; f < 4; f++) {
      short8 vb0 = lds_swz_read(sVT, f * 16 + fr, fk);
      short8 vb1 = lds_swz_read(sVT, f * 16 + fr, 32 + fk);
      acc[f] = __builtin_amdgcn_mfma_f32_16x16x32_bf16(pa0, vb0, acc[f], 0, 0, 0);
      acc[f] = __builtin_amdgcn_mfma_f32_16x16x32_bf16(pa1, vb1, acc[f], 0, 0, 0);
    }
  }

#pragma unroll
  for (int rr = 0; rr < 4; ++rr) {
    const float inv = 1.0f / lrow[rr];
    const int token = b * TT + qw + (lane >> 4) * 4 + rr;
    ushort* yp = yb + (size_t)token * DDIM + h * 64 + fr;
#pragma unroll
    for (int f = 0; f < 4; f++) yp[f * 16] = f2b(acc[f][rr] * inv);
  }
}

// ---------- fused residual add (+ S bf16 split-K planes) + LayerNorm ----------
template <int S>
__global__ __launch_bounds__(256) void add_ln(const float* __restrict__ x,
                                              const ushort* __restrict__ y,
                                              const float* __restrict__ w,
                                              const float* __restrict__ bb,
                                              float* __restrict__ xo,
                                              ushort* __restrict__ xb) {
  const int row = blockIdx.x * 4 + (threadIdx.x >> 6);
  const int lane = threadIdx.x & 63;
  const size_t base = (size_t)row * DDIM + lane * 8;
  f32x4 a0 = *(const f32x4*)(x + base);
  f32x4 a1 = *(const f32x4*)(x + base + 4);
#pragma unroll
  for (int s = 0; s < S; ++s) {
    short8 v = *(const short8*)(y + (size_t)s * MM * DDIM + base);
    f32x4 p0 = { b2f((unsigned short)v[0]), b2f((unsigned short)v[1]),
                 b2f((unsigned short)v[2]), b2f((unsigned short)v[3]) };
    f32x4 p1 = { b2f((unsigned short)v[4]), b2f((unsigned short)v[5]),
                 b2f((unsigned short)v[6]), b2f((unsigned short)v[7]) };
    a0 += p0; a1 += p1;
  }
  float sm = (a0[0] + a0[1] + a0[2] + a0[3]) + (a1[0] + a1[1] + a1[2] + a1[3]);
  f32x4 q0 = a0 * a0, q1 = a1 * a1;
  float ss = (q0[0] + q0[1] + q0[2] + q0[3]) + (q1[0] + q1[1] + q1[2] + q1[3]);
#pragma unroll
  for (int o = 1; o < 64; o <<= 1) {
    sm += __shfl_xor(sm, o);
    ss += __shfl_xor(ss, o);
  }
  const float mu = sm * (1.0f / DDIM);
  const float var = ss * (1.0f / DDIM) - mu * mu;
  const float rs = rsqrtf(var + 1e-5f);
  const int c = lane * 8;
  f32x4 w0 = *(const f32x4*)(w + c), w1 = *(const f32x4*)(w + c + 4);
  f32x4 b0 = *(const f32x4*)(bb + c), b1 = *(const f32x4*)(bb + c + 4);
  f32x4 o0 = (a0 - mu) * rs * w0 + b0;
  f32x4 o1 = (a1 - mu) * rs * w1 + b1;
  *(f32x4*)(xo + base) = o0;
  *(f32x4*)(xo + base + 4) = o1;
  ushort4 u0 = { f2b(o0[0]), f2b(o0[1]), f2b(o0[2]), f2b(o0[3]) };
  ushort4 u1 = { f2b(o1[0]), f2b(o1[1]), f2b(o1[2]), f2b(o1[3]) };
  *(ushort4*)(xb + base) = u0;
  *(ushort4*)(xb + base + 4) = u1;
}

// ---------- launch ----------
extern "C" void kernel_launch(void* const* d_in, const int* in_sizes, int n_in,
                              void* d_out, int out_size, void* d_ws, size_t ws_size,
                              hipStream_t stream) {
  const int*   idx  = (const int*)d_in[0];
  const float* wte  = (const float*)d_in[1];
  const float* wpe  = (const float*)d_in[2];
  const float* aw   = (const float*)d_in[3];
  const float* ab   = (const float*)d_in[4];
  const float* pw   = (const float*)d_in[5];
  const float* pb   = (const float*)d_in[6];
  const float* fw   = (const float*)d_in[7];
  const float* fb   = (const float*)d_in[8];
  const float* f2w  = (const float*)d_in[9];
  const float* f2bi = (const float*)d_in[10];
  const float* l1w  = (const float*)d_in[11];
  const float* l1b  = (const float*)d_in[12];
  const float* l2w  = (const float*)d_in[13];
  const float* l2b  = (const float*)d_in[14];
  const float* lnfw = (const float*)d_in[15];
  const float* lnfb = (const float*)d_in[16];

  char* ws = (char*)d_ws;
  size_t off = 0;
  auto take = [&](size_t bytes) -> void* {
    void* p = ws + off;
    off += (bytes + 255) & ~(size_t)255;
    return p;
  };
  ushort* wte_b = (ushort*)take((size_t)VV * DDIM * 2);
  ushort* aw_b  = (ushort*)take((size_t)LL * 3 * DDIM * DDIM * 2);
  ushort* pw_b  = (ushort*)take((size_t)LL * DDIM * DDIM * 2);
  ushort* fw_b  = (ushort*)take((size_t)LL * FF * DDIM * 2);
  ushort* f2w_b = (ushort*)take((size_t)LL * DDIM * FF * 2);
  float*  x     = (float*)take((size_t)MM * DDIM * 4);
  ushort* xb    = (ushort*)take((size_t)MM * DDIM * 2);
  ushort* qkv_b = (ushort*)take((size_t)MM * 3 * DDIM * 2);
  ushort* yb    = (ushort*)take((size_t)MM * DDIM * 2);
  ushort* tmp_b = (ushort*)take((size_t)2 * MM * DDIM * 2);  // 2 bf16 split-K planes
  ushort* hb    = (ushort*)take((size_t)MM * FF * 2);

  cvt_all<<<dim3((unsigned)(CW4 / 4 / 256)), dim3(256), 0, stream>>>(
      wte, aw, pw, fw, f2w, wte_b);

  embed_kernel<<<dim3(MM), dim3(128), 0, stream>>>(idx, wte, wpe, x, xb);

  for (int l = 0; l < LL; ++l) {
    gemm_bt64<0, 1, 128, 64, 1, 512><<<dim3(24, 24), dim3(512), 0, stream>>>(
        xb, aw_b + (size_t)l * 3 * DDIM * DDIM, ab + (size_t)l * 3 * DDIM, qkv_b, 3 * DDIM, DDIM);
    attn_mfma<<<dim3(TT / 64, BB * 8), dim3(256), 0, stream>>>(qkv_b, yb);
    gemm_bt64<0, 1, 64, 64, 2, 256><<<dim3(8, 48, 2), dim3(256), 0, stream>>>(
        yb, pw_b + (size_t)l * DDIM * DDIM, pb + (size_t)l * DDIM, tmp_b, DDIM, DDIM);
    add_ln<2><<<dim3(MM / 4), dim3(256), 0, stream>>>(
        x, tmp_b, l1w + (size_t)l * DDIM, l1b + (size_t)l * DDIM, x, xb);
    gemm_bt64<1, 1, 128, 64, 1, 512><<<dim3(32, 24), dim3(512), 0, stream>>>(
        xb, fw_b + (size_t)l * FF * DDIM, fb + (size_t)l * FF, hb, FF, DDIM);
    gemm_bt64<0, 1, 64, 64, 2, 256><<<dim3(8, 48, 2), dim3(256), 0, stream>>>(
        hb, f2w_b + (size_t)l * DDIM * FF, f2bi + (size_t)l * DDIM, tmp_b, DDIM, FF);
    add_ln<2><<<dim3(MM / 4), dim3(256), 0, stream>>>(
        x, tmp_b, l2w + (size_t)l * DDIM, l2b + (size_t)l * DDIM, x, xb);
  }
  add_ln<0><<<dim3(MM / 4), dim3(256), 0, stream>>>(x, nullptr, lnfw, lnfb, x, xb);

  gemm_head<<<dim3((VV / 128) * 24), dim3(256), 0, stream>>>(
      xb, wte_b, (float*)d_out, VV, DDIM);
}

// Round 11
// 835.558 us; speedup vs baseline: 1.1242x; 1.0240x over previous
//
#include <hip/hip_runtime.h>
#include <hip/hip_bf16.h>

#define AS1 __attribute__((address_space(1)))
#define AS3 __attribute__((address_space(3)))

typedef __attribute__((ext_vector_type(8))) short short8;
typedef __attribute__((ext_vector_type(4))) float f32x4;

constexpr int BB = 4, TT = 768, DDIM = 512, LL = 6, VV = 50304, FF = 2048;
constexpr int MM = BB * TT;  // 3072 rows of the activation matrix

// ---------- helpers ----------
__device__ inline unsigned short f2b(float f) {
  union { float f; unsigned u; } a; a.f = f;
  unsigned u = a.u;
  return (unsigned short)((u + 0x7FFFu + ((u >> 16) & 1u)) >> 16);  // RNE
}
__device__ inline float b2f(unsigned short u) {
  union { unsigned u; float f; } a; a.u = ((unsigned)u) << 16; return a.f;
}

// ---------- fused f32 -> bf16 convert of all 5 weight tensors ----------
constexpr size_t CW0 = (size_t)VV * DDIM;                  // wte
constexpr size_t CW1 = CW0 + (size_t)LL * 3 * DDIM * DDIM; // + c_attn_w
constexpr size_t CW2 = CW1 + (size_t)LL * DDIM * DDIM;     // + c_proj_w
constexpr size_t CW3 = CW2 + (size_t)LL * FF * DDIM;       // + fc_w
constexpr size_t CW4 = CW3 + (size_t)LL * DDIM * FF;       // + fc2_w

__global__ void cvt_all(const float* __restrict__ wte, const float* __restrict__ aw,
                        const float* __restrict__ pw, const float* __restrict__ fw,
                        const float* __restrict__ f2w, ushort* __restrict__ out) {
  size_t i = ((size_t)blockIdx.x * 256 + threadIdx.x) * 4;
  if (i >= CW4) return;
  const float* src; size_t base;
  if (i < CW0)      { src = wte; base = 0; }
  else if (i < CW1) { src = aw;  base = CW0; }
  else if (i < CW2) { src = pw;  base = CW1; }
  else if (i < CW3) { src = fw;  base = CW2; }
  else              { src = f2w; base = CW3; }
  float4 v = *(const float4*)(src + (i - base));
  ushort4 o = { f2b(v.x), f2b(v.y), f2b(v.z), f2b(v.w) };
  *(ushort4*)(out + i) = o;
}

// ---------- embedding: xb = bf16(wte[idx] + wpe[t]) ----------
__global__ void embed_kernel(const int* __restrict__ idx, const float* __restrict__ wte,
                             const float* __restrict__ wpe, ushort* __restrict__ xb) {
  int row = blockIdx.x;
  int t = row % TT;
  int tok = idx[row];
  int c = threadIdx.x * 4;
  float4 a = *(const float4*)(wte + (size_t)tok * DDIM + c);
  float4 p = *(const float4*)(wpe + (size_t)t * DDIM + c);
  a.x += p.x; a.y += p.y; a.z += p.z; a.w += p.w;
  ushort4 o = { f2b(a.x), f2b(a.y), f2b(a.z), f2b(a.w) };
  *(ushort4*)(xb + (size_t)row * DDIM + c) = o;
}

// ---------- layer GEMM: BK=64, swizzled LDS, dbuf 2-phase, optional split-K ----
// C[M,N] (or partial plane z) = A[M,K-chunk] * Bw[N,K-chunk]^T (+ bias on z==0)
// LDS layout: row-major [row][64 bf16 = 128B], byte swizzle: slot ^= (row&7).
// global_load_lds writes linearly (lane*16B) so the GLOBAL source chunk is
// inverse-swizzled per-lane (rule #21: both-sides-or-neither).
template <int RELU, int OUTBF16, int BM, int BN, int SPLITK, int NT>
__global__ __launch_bounds__(NT) void gemm_bt64(
    const ushort* __restrict__ A, const ushort* __restrict__ Bw,
    const float* __restrict__ bias, void* __restrict__ Cv, int Ndim, int K) {
  constexpr int WROWS = (NT == 512) ? 4 : 2;
  constexpr int WTM = BM / WROWS, WTN = BN / 2;
  constexpr int MI = WTM / 16, NJ = WTN / 16;
  constexpr int RPI = NT / 8;                   // rows per gload_lds instruction
  __shared__ ushort sA[2][BM * 64];
  __shared__ ushort sB[2][BN * 64];
  const int tid = threadIdx.x;
  const int wid = tid >> 6, lane = tid & 63;
  const int m0 = blockIdx.y * BM, n0 = blockIdx.x * BN;
  const int kchunk = K / SPLITK;
  const int ks0 = (SPLITK > 1) ? blockIdx.z * kchunk : 0;
  const int wm = (wid >> 1) * WTM, wn = (wid & 1) * WTN;

  f32x4 zero = {0.f, 0.f, 0.f, 0.f};
  f32x4 acc[MI][NJ];
#pragma unroll
  for (int i = 0; i < MI; i++)
#pragma unroll
    for (int j = 0; j < NJ; j++) acc[i][j] = zero;

  const int r = tid >> 3;
  const int cg = ((tid & 7) ^ (r & 7)) * 8;
  const ushort* gA = A + (size_t)(m0 + r) * K + ks0 + cg;
  const ushort* gB = Bw + (size_t)(n0 + r) * K + ks0 + cg;

  auto stage = [&](int buf, int kk) {
    const ushort* a0 = gA + kk * 64;
    const ushort* b0 = gB + kk * 64;
    ushort* dA = &sA[buf][0] + wid * 512;   // wave-uniform base; HW adds lane*16B
    ushort* dB = &sB[buf][0] + wid * 512;
#pragma unroll
    for (int p = 0; p < BM / RPI; p++)
      __builtin_amdgcn_global_load_lds((const AS1 void*)(a0 + (size_t)p * RPI * K),
                                       (AS3 void*)(dA + p * RPI * 64), 16, 0, 0);
#pragma unroll
    for (int p = 0; p < BN / RPI; p++)
      __builtin_amdgcn_global_load_lds((const AS1 void*)(b0 + (size_t)p * RPI * K),
                                       (AS3 void*)(dB + p * RPI * 64), 16, 0, 0);
  };

  const int fr = lane & 15;
  const int fk = (lane >> 4) * 8;
  auto ldfrag = [&](const ushort* s, int rowbase, int sub) -> short8 {
    const int row = rowbase + fr;
    const int off = row * 128 + ((sub * 64 + fk * 2) ^ ((fr & 7) << 4));
    return *(const short8*)((const char*)s + off);
  };

  const int nK = kchunk >> 6;
  stage(0, 0);
  __syncthreads();
  int buf = 0;
  for (int kk = 0; kk < nK; ++kk) {
    if (kk + 1 < nK) stage(buf ^ 1, kk + 1);
    short8 af[MI][2], bf[NJ][2];
#pragma unroll
    for (int i = 0; i < MI; i++)
#pragma unroll
      for (int s = 0; s < 2; s++) af[i][s] = ldfrag(&sA[buf][0], wm + i * 16, s);
#pragma unroll
    for (int j = 0; j < NJ; j++)
#pragma unroll
      for (int s = 0; s < 2; s++) bf[j][s] = ldfrag(&sB[buf][0], wn + j * 16, s);
#pragma unroll
    for (int i = 0; i < MI; i++)
#pragma unroll
      for (int j = 0; j < NJ; j++)
#pragma unroll
        for (int s = 0; s < 2; s++)
          acc[i][j] = __builtin_amdgcn_mfma_f32_16x16x32_bf16(af[i][s], bf[j][s], acc[i][j], 0, 0, 0);
    __syncthreads();
    buf ^= 1;
  }

  const int cr = (lane >> 4) * 4;
  const int cc = lane & 15;
  const size_t zoff = (SPLITK > 1) ? (size_t)blockIdx.z * MM * Ndim : 0;
  ushort* Cb = (ushort*)Cv + zoff;
  float*  Cf = (float*)Cv + zoff;
#pragma unroll
  for (int j = 0; j < NJ; j++) {
    const int gcol = n0 + wn + j * 16 + cc;
    const float bv = (bias && (SPLITK == 1 || blockIdx.z == 0)) ? bias[gcol] : 0.0f;
#pragma unroll
    for (int i = 0; i < MI; i++) {
      const int grow = m0 + wm + i * 16 + cr;
#pragma unroll
      for (int rr = 0; rr < 4; ++rr) {
        float v = acc[i][j][rr] + bv;
        if (RELU) v = fmaxf(v, 0.0f);
        if (OUTBF16)
          Cb[(size_t)(grow + rr) * Ndim + gcol] = f2b(v);
        else
          Cf[(size_t)(grow + rr) * Ndim + gcol] = v;
      }
    }
  }
}

// ---------- head GEMM (BK=32, 128x128, XCD-swizzled, dbuf 2-phase) ----------
__global__ __launch_bounds__(256) void gemm_head(
    const ushort* __restrict__ A, const ushort* __restrict__ Bw,
    float* __restrict__ Cv, int Ndim, int K) {
  __shared__ ushort sA[2][128 * 32];
  __shared__ ushort sB[2][128 * 32];
  const int tid = threadIdx.x;
  const int wid = tid >> 6, lane = tid & 63;
  int id = blockIdx.x;
  int v = (id >> 3) + (id & 7) * ((int)gridDim.x >> 3);
  const int m0 = (v % 24) * 128;       // same-B blocks consecutive per XCD
  const int n0 = (v / 24) * 128;
  const int wm = (wid >> 1) * 64, wn = (wid & 1) * 64;

  f32x4 zero = {0.f, 0.f, 0.f, 0.f};
  f32x4 acc[4][4];
#pragma unroll
  for (int i = 0; i < 4; i++)
#pragma unroll
    for (int j = 0; j < 4; j++) acc[i][j] = zero;

  const int r4 = tid >> 2;
  const int c8 = (tid & 3) * 8;
  const ushort* gA = A + (size_t)(m0 + r4) * K + c8;
  const ushort* gB = Bw + (size_t)(n0 + r4) * K + c8;
  const size_t K64 = (size_t)64 * K;

  auto stage = [&](int buf, int kk) {
    const ushort* a0 = gA + kk * 32;
    const ushort* b0 = gB + kk * 32;
    ushort* dA = &sA[buf][0] + wid * 512;
    ushort* dB = &sB[buf][0] + wid * 512;
#pragma unroll
    for (int i = 0; i < 2; i++)
      __builtin_amdgcn_global_load_lds((const AS1 void*)(a0 + (size_t)i * K64),
                                       (AS3 void*)(dA + i * 2048), 16, 0, 0);
#pragma unroll
    for (int i = 0; i < 2; i++)
      __builtin_amdgcn_global_load_lds((const AS1 void*)(b0 + (size_t)i * K64),
                                       (AS3 void*)(dB + i * 2048), 16, 0, 0);
  };

  const int fr = lane & 15;
  const int fk = (lane >> 4) * 8;
  const int nK = K >> 5;
  stage(0, 0);
  __syncthreads();
  int buf = 0;
  for (int kk = 0; kk < nK; ++kk) {
    if (kk + 1 < nK) stage(buf ^ 1, kk + 1);
    const ushort* pa0 = &sA[buf][0] + (wm + fr) * 32 + fk;
    const ushort* pb0 = &sB[buf][0] + (wn + fr) * 32 + fk;
    short8 af[4], bf[4];
#pragma unroll
    for (int i = 0; i < 4; i++) af[i] = *(const short8*)(pa0 + i * 16 * 32);
#pragma unroll
    for (int j = 0; j < 4; j++) bf[j] = *(const short8*)(pb0 + j * 16 * 32);
#pragma unroll
    for (int i = 0; i < 4; i++)
#pragma unroll
      for (int j = 0; j < 4; j++)
        acc[i][j] = __builtin_amdgcn_mfma_f32_16x16x32_bf16(af[i], bf[j], acc[i][j], 0, 0, 0);
    __syncthreads();
    buf ^= 1;
  }

  const int cr = (lane >> 4) * 4;
  const int cc = lane & 15;
#pragma unroll
  for (int j = 0; j < 4; j++) {
    const int gcol = n0 + wn + j * 16 + cc;
#pragma unroll
    for (int i = 0; i < 4; i++) {
      const int grow = m0 + wm + i * 16 + cr;
#pragma unroll
      for (int rr = 0; rr < 4; ++rr)
        Cv[(size_t)(grow + rr) * Ndim + gcol] = acc[i][j][rr];
    }
  }
}

// ---------- MFMA fused causal attention ----------
__device__ inline short8 lds_swz_read(const ushort* base, int row, int elem) {
  return *(const short8*)((const char*)base + row * 128 + ((elem * 2) ^ ((row & 7) << 4)));
}

__global__ __launch_bounds__(256) void attn_mfma(const ushort* __restrict__ qkv,
                                                 ushort* __restrict__ yb) {
  __shared__ ushort sK[64 * 64];
  __shared__ ushort sVT[64 * 64];
  __shared__ ushort sP[4 * 16 * 64];
  const int tid = threadIdx.x;
  const int wid = tid >> 6, lane = tid & 63;
  const int qt = blockIdx.x;
  const int b = blockIdx.y >> 3, h = blockIdx.y & 7;
  const int q0 = qt * 64;
  const int qw = q0 + wid * 16;

  const int fr = lane & 15;
  const int fk = (lane >> 4) * 8;
  ushort* sPw = sP + wid * 16 * 64;

  short8 qf[2];
  {
    const ushort* qp = qkv + (size_t)(b * TT + qw + fr) * 1536 + h * 64;
    qf[0] = *(const short8*)(qp + fk);
    qf[1] = *(const short8*)(qp + 32 + fk);
  }

  const int r4 = tid >> 2;           // K staging: row, 16-elem slice
  const int c32 = (tid & 3) * 16;
  const int kb = (tid >> 4) * 4;     // V staging: 4 k-rows
  const int db = (tid & 15) * 4;     // 4 d-cols

  f32x4 zero = {0.f, 0.f, 0.f, 0.f};
  f32x4 acc[4] = {zero, zero, zero, zero};
  float mrow[4] = {-INFINITY, -INFINITY, -INFINITY, -INFINITY};
  float lrow[4] = {0.f, 0.f, 0.f, 0.f};

  for (int kt = 0; kt <= qt; ++kt) {
    __syncthreads();
    const int k0 = kt * 64;
    {  // K tile: swizzled b128 writes
      const ushort* kp = qkv + (size_t)(b * TT + k0 + r4) * 1536 + 512 + h * 64 + c32;
      short8 kv0 = *(const short8*)kp;
      short8 kv1 = *(const short8*)(kp + 8);
      char* skb = (char*)sK + r4 * 128;
      *(short8*)(skb + ((c32 * 2) ^ ((r4 & 7) << 4))) = kv0;
      *(short8*)(skb + ((c32 * 2 + 16) ^ ((r4 & 7) << 4))) = kv1;
      // V^T tile: 4x4 in-register transpose, 4x ds_write_b64
      const ushort* vp = qkv + (size_t)(b * TT + k0 + kb) * 1536 + 1024 + h * 64 + db;
      ushort4 L0 = *(const ushort4*)vp;
      ushort4 L1 = *(const ushort4*)(vp + 1536);
      ushort4 L2 = *(const ushort4*)(vp + 3072);
      ushort4 L3 = *(const ushort4*)(vp + 4608);
      ushort4 c0 = { L0.x, L1.x, L2.x, L3.x };
      ushort4 c1 = { L0.y, L1.y, L2.y, L3.y };
      ushort4 c2 = { L0.z, L1.z, L2.z, L3.z };
      ushort4 c3 = { L0.w, L1.w, L2.w, L3.w };
      *(ushort4*)((char*)sVT + (db + 0) * 128 + ((kb * 2) ^ (((db + 0) & 7) << 4))) = c0;
      *(ushort4*)((char*)sVT + (db + 1) * 128 + ((kb * 2) ^ (((db + 1) & 7) << 4))) = c1;
      *(ushort4*)((char*)sVT + (db + 2) * 128 + ((kb * 2) ^ (((db + 2) & 7) << 4))) = c2;
      *(ushort4*)((char*)sVT + (db + 3) * 128 + ((kb * 2) ^ (((db + 3) & 7) << 4))) = c3;
    }
    __syncthreads();

    f32x4 sfr[4];
#pragma unroll
    for (int j = 0; j < 4; j++) {
      short8 kb0 = lds_swz_read(sK, j * 16 + fr, fk);
      short8 kb1 = lds_swz_read(sK, j * 16 + fr, 32 + fk);
      f32x4 s = __builtin_amdgcn_mfma_f32_16x16x32_bf16(qf[0], kb0, zero, 0, 0, 0);
      s = __builtin_amdgcn_mfma_f32_16x16x32_bf16(qf[1], kb1, s, 0, 0, 0);
      sfr[j] = s * 0.125f;
    }
    if (kt == qt) {
#pragma unroll
      for (int j = 0; j < 4; j++)
#pragma unroll
        for (int rr = 0; rr < 4; ++rr)
          if (j * 16 + fr > wid * 16 + (lane >> 4) * 4 + rr) sfr[j][rr] = -INFINITY;
    }

    float scl[4];
#pragma unroll
    for (int rr = 0; rr < 4; ++rr) {
      float t = fmaxf(fmaxf(sfr[0][rr], sfr[1][rr]), fmaxf(sfr[2][rr], sfr[3][rr]));
      t = fmaxf(t, __shfl_xor(t, 1));
      t = fmaxf(t, __shfl_xor(t, 2));
      t = fmaxf(t, __shfl_xor(t, 4));
      t = fmaxf(t, __shfl_xor(t, 8));
      const float mnew = fmaxf(mrow[rr], t);
      scl[rr] = __expf(mrow[rr] - mnew);
      mrow[rr] = mnew;
      float ps = 0.f;
#pragma unroll
      for (int j = 0; j < 4; j++) {
        float p = __expf(sfr[j][rr] - mnew);
        sfr[j][rr] = p;
        ps += p;
      }
      ps += __shfl_xor(ps, 1);
      ps += __shfl_xor(ps, 2);
      ps += __shfl_xor(ps, 4);
      ps += __shfl_xor(ps, 8);
      lrow[rr] = lrow[rr] * scl[rr] + ps;
    }

#pragma unroll
    for (int j = 0; j < 4; j++)
#pragma unroll
      for (int rr = 0; rr < 4; ++rr) {
        int q = (lane >> 4) * 4 + rr, k = j * 16 + fr;
        *(ushort*)((char*)sPw + q * 128 + ((k * 2) ^ ((q & 7) << 4))) = f2b(sfr[j][rr]);
      }

#pragma unroll
    for (int f = 0; f < 4; f++)
#pragma unroll
      for (int rr = 0; rr < 4; ++rr) acc[f][rr] *= scl[rr];

    short8 pa0 = lds_swz_read(sPw, fr, fk);
    short8 pa1 = lds_swz_read(sPw, fr, 32 + fk);
#pragma unroll
    for (int f = 0; f < 4; f++) {
      short8 vb0 = lds_swz_read(sVT, f * 16 + fr, fk);
      short8 vb1 = lds_swz_read(sVT, f * 16 + fr, 32 + fk);
      acc[f] = __builtin_amdgcn_mfma_f32_16x16x32_bf16(pa0, vb0, acc[f], 0, 0, 0);
      acc[f] = __builtin_amdgcn_mfma_f32_16x16x32_bf16(pa1, vb1, acc[f], 0, 0, 0);
    }
  }

#pragma unroll
  for (int rr = 0; rr < 4; ++rr) {
    const float inv = 1.0f / lrow[rr];
    const int token = b * TT + qw + (lane >> 4) * 4 + rr;
    ushort* yp = yb + (size_t)token * DDIM + h * 64 + fr;
#pragma unroll
    for (int f = 0; f < 4; f++) yp[f * 16] = f2b(acc[f][rr] * inv);
  }
}

// ---------- fused residual add (+ S bf16 split-K planes) + LayerNorm ----------
// Residual stream is bf16-only (post-LN unit-scale values; LN renormalizes,
// validated in R8: absmax unchanged at 0.03125).
template <int S>
__global__ __launch_bounds__(256) void add_ln(const ushort* __restrict__ xr,
                                              const ushort* __restrict__ y,
                                              const float* __restrict__ w,
                                              const float* __restrict__ bb,
                                              ushort* __restrict__ xo) {
  const int row = blockIdx.x * 4 + (threadIdx.x >> 6);
  const int lane = threadIdx.x & 63;
  const size_t base = (size_t)row * DDIM + lane * 8;
  short8 xv = *(const short8*)(xr + base);
  f32x4 a0 = { b2f((unsigned short)xv[0]), b2f((unsigned short)xv[1]),
               b2f((unsigned short)xv[2]), b2f((unsigned short)xv[3]) };
  f32x4 a1 = { b2f((unsigned short)xv[4]), b2f((unsigned short)xv[5]),
               b2f((unsigned short)xv[6]), b2f((unsigned short)xv[7]) };
#pragma unroll
  for (int s = 0; s < S; ++s) {
    short8 v = *(const short8*)(y + (size_t)s * MM * DDIM + base);
    f32x4 p0 = { b2f((unsigned short)v[0]), b2f((unsigned short)v[1]),
                 b2f((unsigned short)v[2]), b2f((unsigned short)v[3]) };
    f32x4 p1 = { b2f((unsigned short)v[4]), b2f((unsigned short)v[5]),
                 b2f((unsigned short)v[6]), b2f((unsigned short)v[7]) };
    a0 += p0; a1 += p1;
  }
  float sm = (a0[0] + a0[1] + a0[2] + a0[3]) + (a1[0] + a1[1] + a1[2] + a1[3]);
  f32x4 q0 = a0 * a0, q1 = a1 * a1;
  float ss = (q0[0] + q0[1] + q0[2] + q0[3]) + (q1[0] + q1[1] + q1[2] + q1[3]);
#pragma unroll
  for (int o = 1; o < 64; o <<= 1) {
    sm += __shfl_xor(sm, o);
    ss += __shfl_xor(ss, o);
  }
  const float mu = sm * (1.0f / DDIM);
  const float var = ss * (1.0f / DDIM) - mu * mu;
  const float rs = rsqrtf(var + 1e-5f);
  const int c = lane * 8;
  f32x4 w0 = *(const f32x4*)(w + c), w1 = *(const f32x4*)(w + c + 4);
  f32x4 b0 = *(const f32x4*)(bb + c), b1 = *(const f32x4*)(bb + c + 4);
  f32x4 o0 = (a0 - mu) * rs * w0 + b0;
  f32x4 o1 = (a1 - mu) * rs * w1 + b1;
  short8 u;
  u[0] = (short)f2b(o0[0]); u[1] = (short)f2b(o0[1]);
  u[2] = (short)f2b(o0[2]); u[3] = (short)f2b(o0[3]);
  u[4] = (short)f2b(o1[0]); u[5] = (short)f2b(o1[1]);
  u[6] = (short)f2b(o1[2]); u[7] = (short)f2b(o1[3]);
  *(short8*)(xo + base) = u;
}

// ---------- launch ----------
extern "C" void kernel_launch(void* const* d_in, const int* in_sizes, int n_in,
                              void* d_out, int out_size, void* d_ws, size_t ws_size,
                              hipStream_t stream) {
  const int*   idx  = (const int*)d_in[0];
  const float* wte  = (const float*)d_in[1];
  const float* wpe  = (const float*)d_in[2];
  const float* aw   = (const float*)d_in[3];
  const float* ab   = (const float*)d_in[4];
  const float* pw   = (const float*)d_in[5];
  const float* pb   = (const float*)d_in[6];
  const float* fw   = (const float*)d_in[7];
  const float* fb   = (const float*)d_in[8];
  const float* f2w  = (const float*)d_in[9];
  const float* f2bi = (const float*)d_in[10];
  const float* l1w  = (const float*)d_in[11];
  const float* l1b  = (const float*)d_in[12];
  const float* l2w  = (const float*)d_in[13];
  const float* l2b  = (const float*)d_in[14];
  const float* lnfw = (const float*)d_in[15];
  const float* lnfb = (const float*)d_in[16];

  char* ws = (char*)d_ws;
  size_t off = 0;
  auto take = [&](size_t bytes) -> void* {
    void* p = ws + off;
    off += (bytes + 255) & ~(size_t)255;
    return p;
  };
  ushort* wte_b = (ushort*)take((size_t)VV * DDIM * 2);
  ushort* aw_b  = (ushort*)take((size_t)LL * 3 * DDIM * DDIM * 2);
  ushort* pw_b  = (ushort*)take((size_t)LL * DDIM * DDIM * 2);
  ushort* fw_b  = (ushort*)take((size_t)LL * FF * DDIM * 2);
  ushort* f2w_b = (ushort*)take((size_t)LL * DDIM * FF * 2);
  ushort* xb    = (ushort*)take((size_t)MM * DDIM * 2);
  ushort* qkv_b = (ushort*)take((size_t)MM * 3 * DDIM * 2);
  ushort* yb    = (ushort*)take((size_t)MM * DDIM * 2);
  ushort* tmp_b = (ushort*)take((size_t)2 * MM * DDIM * 2);  // 2 bf16 split-K planes
  ushort* hb    = (ushort*)take((size_t)MM * FF * 2);

  cvt_all<<<dim3((unsigned)(CW4 / 4 / 256)), dim3(256), 0, stream>>>(
      wte, aw, pw, fw, f2w, wte_b);

  embed_kernel<<<dim3(MM), dim3(128), 0, stream>>>(idx, wte, wpe, xb);

  for (int l = 0; l < LL; ++l) {
    gemm_bt64<0, 1, 128, 64, 1, 512><<<dim3(24, 24), dim3(512), 0, stream>>>(
        xb, aw_b + (size_t)l * 3 * DDIM * DDIM, ab + (size_t)l * 3 * DDIM, qkv_b, 3 * DDIM, DDIM);
    attn_mfma<<<dim3(TT / 64, BB * 8), dim3(256), 0, stream>>>(qkv_b, yb);
    gemm_bt64<0, 1, 64, 64, 2, 256><<<dim3(8, 48, 2), dim3(256), 0, stream>>>(
        yb, pw_b + (size_t)l * DDIM * DDIM, pb + (size_t)l * DDIM, tmp_b, DDIM, DDIM);
    add_ln<2><<<dim3(MM / 4), dim3(256), 0, stream>>>(
        xb, tmp_b, l1w + (size_t)l * DDIM, l1b + (size_t)l * DDIM, xb);
    gemm_bt64<1, 1, 128, 64, 1, 512><<<dim3(32, 24), dim3(512), 0, stream>>>(
        xb, fw_b + (size_t)l * FF * DDIM, fb + (size_t)l * FF, hb, FF, DDIM);
    gemm_bt64<0, 1, 64, 64, 2, 256><<<dim3(8, 48, 2), dim3(256), 0, stream>>>(
        hb, f2w_b + (size_t)l * DDIM * FF, f2bi + (size_t)l * DDIM, tmp_b, DDIM, FF);
    add_ln<2><<<dim3(MM / 4), dim3(256), 0, stream>>>(
        xb, tmp_b, l2w + (size_t)l * DDIM, l2b + (size_t)l * DDIM, xb);
  }
  add_ln<0><<<dim3(MM / 4), dim3(256), 0, stream>>>(xb, nullptr, lnfw, lnfb, xb);

  gemm_head<<<dim3((VV / 128) * 24), dim3(256), 0, stream>>>(
      xb, wte_b, (float*)d_out, VV, DDIM);
}

// Round 12
// 833.130 us; speedup vs baseline: 1.1274x; 1.0029x over previous
//
#include <hip/hip_runtime.h>
#include <hip/hip_bf16.h>

#define AS1 __attribute__((address_space(1)))
#define AS3 __attribute__((address_space(3)))

typedef __attribute__((ext_vector_type(8))) short short8;
typedef __attribute__((ext_vector_type(4))) float f32x4;

constexpr int BB = 4, TT = 768, DDIM = 512, LL = 6, VV = 50304, FF = 2048;
constexpr int MM = BB * TT;  // 3072 rows of the activation matrix

// ---------- helpers ----------
__device__ inline unsigned short f2b(float f) {
  union { float f; unsigned u; } a; a.f = f;
  unsigned u = a.u;
  return (unsigned short)((u + 0x7FFFu + ((u >> 16) & 1u)) >> 16);  // RNE
}
__device__ inline float b2f(unsigned short u) {
  union { unsigned u; float f; } a; a.u = ((unsigned)u) << 16; return a.f;
}

// ---------- fused f32 -> bf16 convert of all 5 weight tensors ----------
constexpr size_t CW0 = (size_t)VV * DDIM;                  // wte
constexpr size_t CW1 = CW0 + (size_t)LL * 3 * DDIM * DDIM; // + c_attn_w
constexpr size_t CW2 = CW1 + (size_t)LL * DDIM * DDIM;     // + c_proj_w
constexpr size_t CW3 = CW2 + (size_t)LL * FF * DDIM;       // + fc_w
constexpr size_t CW4 = CW3 + (size_t)LL * DDIM * FF;       // + fc2_w

__global__ void cvt_all(const float* __restrict__ wte, const float* __restrict__ aw,
                        const float* __restrict__ pw, const float* __restrict__ fw,
                        const float* __restrict__ f2w, ushort* __restrict__ out) {
  size_t i = ((size_t)blockIdx.x * 256 + threadIdx.x) * 4;
  if (i >= CW4) return;
  const float* src; size_t base;
  if (i < CW0)      { src = wte; base = 0; }
  else if (i < CW1) { src = aw;  base = CW0; }
  else if (i < CW2) { src = pw;  base = CW1; }
  else if (i < CW3) { src = fw;  base = CW2; }
  else              { src = f2w; base = CW3; }
  float4 v = *(const float4*)(src + (i - base));
  ushort4 o = { f2b(v.x), f2b(v.y), f2b(v.z), f2b(v.w) };
  *(ushort4*)(out + i) = o;
}

// ---------- embedding: xb = bf16(wte[idx] + wpe[t]) ----------
__global__ void embed_kernel(const int* __restrict__ idx, const float* __restrict__ wte,
                             const float* __restrict__ wpe, ushort* __restrict__ xb) {
  int row = blockIdx.x;
  int t = row % TT;
  int tok = idx[row];
  int c = threadIdx.x * 4;
  float4 a = *(const float4*)(wte + (size_t)tok * DDIM + c);
  float4 p = *(const float4*)(wpe + (size_t)t * DDIM + c);
  a.x += p.x; a.y += p.y; a.z += p.z; a.w += p.w;
  ushort4 o = { f2b(a.x), f2b(a.y), f2b(a.z), f2b(a.w) };
  *(ushort4*)(xb + (size_t)row * DDIM + c) = o;
}

// ---------- layer GEMM: BK=64, swizzled LDS, dbuf 2-phase, optional split-K ----
template <int RELU, int OUTBF16, int BM, int BN, int SPLITK, int NT>
__global__ __launch_bounds__(NT) void gemm_bt64(
    const ushort* __restrict__ A, const ushort* __restrict__ Bw,
    const float* __restrict__ bias, void* __restrict__ Cv, int Ndim, int K) {
  constexpr int WROWS = (NT == 512) ? 4 : 2;
  constexpr int WTM = BM / WROWS, WTN = BN / 2;
  constexpr int MI = WTM / 16, NJ = WTN / 16;
  constexpr int RPI = NT / 8;                   // rows per gload_lds instruction
  __shared__ ushort sA[2][BM * 64];
  __shared__ ushort sB[2][BN * 64];
  const int tid = threadIdx.x;
  const int wid = tid >> 6, lane = tid & 63;
  const int m0 = blockIdx.y * BM, n0 = blockIdx.x * BN;
  const int kchunk = K / SPLITK;
  const int ks0 = (SPLITK > 1) ? blockIdx.z * kchunk : 0;
  const int wm = (wid >> 1) * WTM, wn = (wid & 1) * WTN;

  f32x4 zero = {0.f, 0.f, 0.f, 0.f};
  f32x4 acc[MI][NJ];
#pragma unroll
  for (int i = 0; i < MI; i++)
#pragma unroll
    for (int j = 0; j < NJ; j++) acc[i][j] = zero;

  const int r = tid >> 3;
  const int cg = ((tid & 7) ^ (r & 7)) * 8;
  const ushort* gA = A + (size_t)(m0 + r) * K + ks0 + cg;
  const ushort* gB = Bw + (size_t)(n0 + r) * K + ks0 + cg;

  auto stage = [&](int buf, int kk) {
    const ushort* a0 = gA + kk * 64;
    const ushort* b0 = gB + kk * 64;
    ushort* dA = &sA[buf][0] + wid * 512;   // wave-uniform base; HW adds lane*16B
    ushort* dB = &sB[buf][0] + wid * 512;
#pragma unroll
    for (int p = 0; p < BM / RPI; p++)
      __builtin_amdgcn_global_load_lds((const AS1 void*)(a0 + (size_t)p * RPI * K),
                                       (AS3 void*)(dA + p * RPI * 64), 16, 0, 0);
#pragma unroll
    for (int p = 0; p < BN / RPI; p++)
      __builtin_amdgcn_global_load_lds((const AS1 void*)(b0 + (size_t)p * RPI * K),
                                       (AS3 void*)(dB + p * RPI * 64), 16, 0, 0);
  };

  const int fr = lane & 15;
  const int fk = (lane >> 4) * 8;
  auto ldfrag = [&](const ushort* s, int rowbase, int sub) -> short8 {
    const int row = rowbase + fr;
    const int off = row * 128 + ((sub * 64 + fk * 2) ^ ((fr & 7) << 4));
    return *(const short8*)((const char*)s + off);
  };

  const int nK = kchunk >> 6;
  stage(0, 0);
  __syncthreads();
  int buf = 0;
  for (int kk = 0; kk < nK; ++kk) {
    if (kk + 1 < nK) stage(buf ^ 1, kk + 1);
    short8 af[MI][2], bf[NJ][2];
#pragma unroll
    for (int i = 0; i < MI; i++)
#pragma unroll
      for (int s = 0; s < 2; s++) af[i][s] = ldfrag(&sA[buf][0], wm + i * 16, s);
#pragma unroll
    for (int j = 0; j < NJ; j++)
#pragma unroll
      for (int s = 0; s < 2; s++) bf[j][s] = ldfrag(&sB[buf][0], wn + j * 16, s);
#pragma unroll
    for (int i = 0; i < MI; i++)
#pragma unroll
      for (int j = 0; j < NJ; j++)
#pragma unroll
        for (int s = 0; s < 2; s++)
          acc[i][j] = __builtin_amdgcn_mfma_f32_16x16x32_bf16(af[i][s], bf[j][s], acc[i][j], 0, 0, 0);
    __syncthreads();
    buf ^= 1;
  }

  const int cr = (lane >> 4) * 4;
  const int cc = lane & 15;
  const size_t zoff = (SPLITK > 1) ? (size_t)blockIdx.z * MM * Ndim : 0;
  ushort* Cb = (ushort*)Cv + zoff;
  float*  Cf = (float*)Cv + zoff;
#pragma unroll
  for (int j = 0; j < NJ; j++) {
    const int gcol = n0 + wn + j * 16 + cc;
    const float bv = (bias && (SPLITK == 1 || blockIdx.z == 0)) ? bias[gcol] : 0.0f;
#pragma unroll
    for (int i = 0; i < MI; i++) {
      const int grow = m0 + wm + i * 16 + cr;
#pragma unroll
      for (int rr = 0; rr < 4; ++rr) {
        float v = acc[i][j][rr] + bv;
        if (RELU) v = fmaxf(v, 0.0f);
        if (OUTBF16)
          Cb[(size_t)(grow + rr) * Ndim + gcol] = f2b(v);
        else
          Cf[(size_t)(grow + rr) * Ndim + gcol] = v;
      }
    }
  }
}

// ---------- head GEMM (BK=32, 128x128, XCD-swizzled, dbuf 2-phase) ----------
__global__ __launch_bounds__(256) void gemm_head(
    const ushort* __restrict__ A, const ushort* __restrict__ Bw,
    float* __restrict__ Cv, int Ndim, int K) {
  __shared__ ushort sA[2][128 * 32];
  __shared__ ushort sB[2][128 * 32];
  const int tid = threadIdx.x;
  const int wid = tid >> 6, lane = tid & 63;
  int id = blockIdx.x;
  int v = (id >> 3) + (id & 7) * ((int)gridDim.x >> 3);
  const int m0 = (v % 24) * 128;       // same-B blocks consecutive per XCD
  const int n0 = (v / 24) * 128;
  const int wm = (wid >> 1) * 64, wn = (wid & 1) * 64;

  f32x4 zero = {0.f, 0.f, 0.f, 0.f};
  f32x4 acc[4][4];
#pragma unroll
  for (int i = 0; i < 4; i++)
#pragma unroll
    for (int j = 0; j < 4; j++) acc[i][j] = zero;

  const int r4 = tid >> 2;
  const int c8 = (tid & 3) * 8;
  const ushort* gA = A + (size_t)(m0 + r4) * K + c8;
  const ushort* gB = Bw + (size_t)(n0 + r4) * K + c8;
  const size_t K64 = (size_t)64 * K;

  auto stage = [&](int buf, int kk) {
    const ushort* a0 = gA + kk * 32;
    const ushort* b0 = gB + kk * 32;
    ushort* dA = &sA[buf][0] + wid * 512;
    ushort* dB = &sB[buf][0] + wid * 512;
#pragma unroll
    for (int i = 0; i < 2; i++)
      __builtin_amdgcn_global_load_lds((const AS1 void*)(a0 + (size_t)i * K64),
                                       (AS3 void*)(dA + i * 2048), 16, 0, 0);
#pragma unroll
    for (int i = 0; i < 2; i++)
      __builtin_amdgcn_global_load_lds((const AS1 void*)(b0 + (size_t)i * K64),
                                       (AS3 void*)(dB + i * 2048), 16, 0, 0);
  };

  const int fr = lane & 15;
  const int fk = (lane >> 4) * 8;
  const int nK = K >> 5;
  stage(0, 0);
  __syncthreads();
  int buf = 0;
  for (int kk = 0; kk < nK; ++kk) {
    if (kk + 1 < nK) stage(buf ^ 1, kk + 1);
    const ushort* pa0 = &sA[buf][0] + (wm + fr) * 32 + fk;
    const ushort* pb0 = &sB[buf][0] + (wn + fr) * 32 + fk;
    short8 af[4], bf[4];
#pragma unroll
    for (int i = 0; i < 4; i++) af[i] = *(const short8*)(pa0 + i * 16 * 32);
#pragma unroll
    for (int j = 0; j < 4; j++) bf[j] = *(const short8*)(pb0 + j * 16 * 32);
#pragma unroll
    for (int i = 0; i < 4; i++)
#pragma unroll
      for (int j = 0; j < 4; j++)
        acc[i][j] = __builtin_amdgcn_mfma_f32_16x16x32_bf16(af[i], bf[j], acc[i][j], 0, 0, 0);
    __syncthreads();
    buf ^= 1;
  }

  const int cr = (lane >> 4) * 4;
  const int cc = lane & 15;
#pragma unroll
  for (int j = 0; j < 4; j++) {
    const int gcol = n0 + wn + j * 16 + cc;
#pragma unroll
    for (int i = 0; i < 4; i++) {
      const int grow = m0 + wm + i * 16 + cr;
#pragma unroll
      for (int rr = 0; rr < 4; ++rr)
        Cv[(size_t)(grow + rr) * Ndim + gcol] = acc[i][j][rr];
    }
  }
}

// ---------- MFMA fused causal attention ----------
__device__ inline short8 lds_swz_read(const ushort* base, int row, int elem) {
  return *(const short8*)((const char*)base + row * 128 + ((elem * 2) ^ ((row & 7) << 4)));
}

__global__ __launch_bounds__(256) void attn_mfma(const ushort* __restrict__ qkv,
                                                 ushort* __restrict__ yb) {
  __shared__ ushort sK[64 * 64];
  __shared__ ushort sVT[64 * 64];
  __shared__ ushort sP[4 * 16 * 64];
  const int tid = threadIdx.x;
  const int wid = tid >> 6, lane = tid & 63;
  const int qt = (int)gridDim.x - 1 - (int)blockIdx.x;  // longest blocks first
  const int b = blockIdx.y >> 3, h = blockIdx.y & 7;
  const int q0 = qt * 64;
  const int qw = q0 + wid * 16;

  const int fr = lane & 15;
  const int fk = (lane >> 4) * 8;
  ushort* sPw = sP + wid * 16 * 64;

  short8 qf[2];
  {
    const ushort* qp = qkv + (size_t)(b * TT + qw + fr) * 1536 + h * 64;
    qf[0] = *(const short8*)(qp + fk);
    qf[1] = *(const short8*)(qp + 32 + fk);
  }

  const int r4 = tid >> 2;           // K staging: row, 16-elem slice
  const int c32 = (tid & 3) * 16;
  const int kb = (tid >> 4) * 4;     // V staging: 4 k-rows
  const int db = (tid & 15) * 4;     // 4 d-cols

  f32x4 zero = {0.f, 0.f, 0.f, 0.f};
  f32x4 acc[4] = {zero, zero, zero, zero};
  float mrow[4] = {-INFINITY, -INFINITY, -INFINITY, -INFINITY};
  float lrow[4] = {0.f, 0.f, 0.f, 0.f};

  for (int kt = 0; kt <= qt; ++kt) {
    __syncthreads();
    const int k0 = kt * 64;
    {  // K tile: swizzled b128 writes
      const ushort* kp = qkv + (size_t)(b * TT + k0 + r4) * 1536 + 512 + h * 64 + c32;
      short8 kv0 = *(const short8*)kp;
      short8 kv1 = *(const short8*)(kp + 8);
      char* skb = (char*)sK + r4 * 128;
      *(short8*)(skb + ((c32 * 2) ^ ((r4 & 7) << 4))) = kv0;
      *(short8*)(skb + ((c32 * 2 + 16) ^ ((r4 & 7) << 4))) = kv1;
      // V^T tile: 4x4 in-register transpose, 4x ds_write_b64
      const ushort* vp = qkv + (size_t)(b * TT + k0 + kb) * 1536 + 1024 + h * 64 + db;
      ushort4 L0 = *(const ushort4*)vp;
      ushort4 L1 = *(const ushort4*)(vp + 1536);
      ushort4 L2 = *(const ushort4*)(vp + 3072);
      ushort4 L3 = *(const ushort4*)(vp + 4608);
      ushort4 c0 = { L0.x, L1.x, L2.x, L3.x };
      ushort4 c1 = { L0.y, L1.y, L2.y, L3.y };
      ushort4 c2 = { L0.z, L1.z, L2.z, L3.z };
      ushort4 c3 = { L0.w, L1.w, L2.w, L3.w };
      *(ushort4*)((char*)sVT + (db + 0) * 128 + ((kb * 2) ^ (((db + 0) & 7) << 4))) = c0;
      *(ushort4*)((char*)sVT + (db + 1) * 128 + ((kb * 2) ^ (((db + 1) & 7) << 4))) = c1;
      *(ushort4*)((char*)sVT + (db + 2) * 128 + ((kb * 2) ^ (((db + 2) & 7) << 4))) = c2;
      *(ushort4*)((char*)sVT + (db + 3) * 128 + ((kb * 2) ^ (((db + 3) & 7) << 4))) = c3;
    }
    __syncthreads();

    f32x4 sfr[4];
    __builtin_amdgcn_s_setprio(1);   // T5: attn blocks are independent (m191 +4-7%)
#pragma unroll
    for (int j = 0; j < 4; j++) {
      short8 kb0 = lds_swz_read(sK, j * 16 + fr, fk);
      short8 kb1 = lds_swz_read(sK, j * 16 + fr, 32 + fk);
      f32x4 s = __builtin_amdgcn_mfma_f32_16x16x32_bf16(qf[0], kb0, zero, 0, 0, 0);
      s = __builtin_amdgcn_mfma_f32_16x16x32_bf16(qf[1], kb1, s, 0, 0, 0);
      sfr[j] = s * 0.125f;
    }
    __builtin_amdgcn_s_setprio(0);
    if (kt == qt) {
#pragma unroll
      for (int j = 0; j < 4; j++)
#pragma unroll
        for (int rr = 0; rr < 4; ++rr)
          if (j * 16 + fr > wid * 16 + (lane >> 4) * 4 + rr) sfr[j][rr] = -INFINITY;
    }

    float scl[4];
#pragma unroll
    for (int rr = 0; rr < 4; ++rr) {
      float t = fmaxf(fmaxf(sfr[0][rr], sfr[1][rr]), fmaxf(sfr[2][rr], sfr[3][rr]));
      t = fmaxf(t, __shfl_xor(t, 1));
      t = fmaxf(t, __shfl_xor(t, 2));
      t = fmaxf(t, __shfl_xor(t, 4));
      t = fmaxf(t, __shfl_xor(t, 8));
      const float mnew = fmaxf(mrow[rr], t);
      scl[rr] = __expf(mrow[rr] - mnew);
      mrow[rr] = mnew;
      float ps = 0.f;
#pragma unroll
      for (int j = 0; j < 4; j++) {
        float p = __expf(sfr[j][rr] - mnew);
        sfr[j][rr] = p;
        ps += p;
      }
      ps += __shfl_xor(ps, 1);
      ps += __shfl_xor(ps, 2);
      ps += __shfl_xor(ps, 4);
      ps += __shfl_xor(ps, 8);
      lrow[rr] = lrow[rr] * scl[rr] + ps;
    }

#pragma unroll
    for (int j = 0; j < 4; j++)
#pragma unroll
      for (int rr = 0; rr < 4; ++rr) {
        int q = (lane >> 4) * 4 + rr, k = j * 16 + fr;
        *(ushort*)((char*)sPw + q * 128 + ((k * 2) ^ ((q & 7) << 4))) = f2b(sfr[j][rr]);
      }

#pragma unroll
    for (int f = 0; f < 4; f++)
#pragma unroll
      for (int rr = 0; rr < 4; ++rr) acc[f][rr] *= scl[rr];

    short8 pa0 = lds_swz_read(sPw, fr, fk);
    short8 pa1 = lds_swz_read(sPw, fr, 32 + fk);
    __builtin_amdgcn_s_setprio(1);
#pragma unroll
    for (int f = 0; f < 4; f++) {
      short8 vb0 = lds_swz_read(sVT, f * 16 + fr, fk);
      short8 vb1 = lds_swz_read(sVT, f * 16 + fr, 32 + fk);
      acc[f] = __builtin_amdgcn_mfma_f32_16x16x32_bf16(pa0, vb0, acc[f], 0, 0, 0);
      acc[f] = __builtin_amdgcn_mfma_f32_16x16x32_bf16(pa1, vb1, acc[f], 0, 0, 0);
    }
    __builtin_amdgcn_s_setprio(0);
  }

#pragma unroll
  for (int rr = 0; rr < 4; ++rr) {
    const float inv = 1.0f / lrow[rr];
    const int token = b * TT + qw + (lane >> 4) * 4 + rr;
    ushort* yp = yb + (size_t)token * DDIM + h * 64 + fr;
#pragma unroll
    for (int f = 0; f < 4; f++) yp[f * 16] = f2b(acc[f][rr] * inv);
  }
}

// ---------- fused residual add (+ S bf16 split-K planes) + LayerNorm ----------
template <int S>
__global__ __launch_bounds__(256) void add_ln(const ushort* __restrict__ xr,
                                              const ushort* __restrict__ y,
                                              const float* __restrict__ w,
                                              const float* __restrict__ bb,
                                              ushort* __restrict__ xo) {
  const int row = blockIdx.x * 4 + (threadIdx.x >> 6);
  const int lane = threadIdx.x & 63;
  const size_t base = (size_t)row * DDIM + lane * 8;
  short8 xv = *(const short8*)(xr + base);
  f32x4 a0 = { b2f((unsigned short)xv[0]), b2f((unsigned short)xv[1]),
               b2f((unsigned short)xv[2]), b2f((unsigned short)xv[3]) };
  f32x4 a1 = { b2f((unsigned short)xv[4]), b2f((unsigned short)xv[5]),
               b2f((unsigned short)xv[6]), b2f((unsigned short)xv[7]) };
#pragma unroll
  for (int s = 0; s < S; ++s) {
    short8 v = *(const short8*)(y + (size_t)s * MM * DDIM + base);
    f32x4 p0 = { b2f((unsigned short)v[0]), b2f((unsigned short)v[1]),
                 b2f((unsigned short)v[2]), b2f((unsigned short)v[3]) };
    f32x4 p1 = { b2f((unsigned short)v[4]), b2f((unsigned short)v[5]),
                 b2f((unsigned short)v[6]), b2f((unsigned short)v[7]) };
    a0 += p0; a1 += p1;
  }
  float sm = (a0[0] + a0[1] + a0[2] + a0[3]) + (a1[0] + a1[1] + a1[2] + a1[3]);
  f32x4 q0 = a0 * a0, q1 = a1 * a1;
  float ss = (q0[0] + q0[1] + q0[2] + q0[3]) + (q1[0] + q1[1] + q1[2] + q1[3]);
#pragma unroll
  for (int o = 1; o < 64; o <<= 1) {
    sm += __shfl_xor(sm, o);
    ss += __shfl_xor(ss, o);
  }
  const float mu = sm * (1.0f / DDIM);
  const float var = ss * (1.0f / DDIM) - mu * mu;
  const float rs = rsqrtf(var + 1e-5f);
  const int c = lane * 8;
  f32x4 w0 = *(const f32x4*)(w + c), w1 = *(const f32x4*)(w + c + 4);
  f32x4 b0 = *(const f32x4*)(bb + c), b1 = *(const f32x4*)(bb + c + 4);
  f32x4 o0 = (a0 - mu) * rs * w0 + b0;
  f32x4 o1 = (a1 - mu) * rs * w1 + b1;
  short8 u;
  u[0] = (short)f2b(o0[0]); u[1] = (short)f2b(o0[1]);
  u[2] = (short)f2b(o0[2]); u[3] = (short)f2b(o0[3]);
  u[4] = (short)f2b(o1[0]); u[5] = (short)f2b(o1[1]);
  u[6] = (short)f2b(o1[2]); u[7] = (short)f2b(o1[3]);
  *(short8*)(xo + base) = u;
}

// ---------- launch ----------
extern "C" void kernel_launch(void* const* d_in, const int* in_sizes, int n_in,
                              void* d_out, int out_size, void* d_ws, size_t ws_size,
                              hipStream_t stream) {
  const int*   idx  = (const int*)d_in[0];
  const float* wte  = (const float*)d_in[1];
  const float* wpe  = (const float*)d_in[2];
  const float* aw   = (const float*)d_in[3];
  const float* ab   = (const float*)d_in[4];
  const float* pw   = (const float*)d_in[5];
  const float* pb   = (const float*)d_in[6];
  const float* fw   = (const float*)d_in[7];
  const float* fb   = (const float*)d_in[8];
  const float* f2w  = (const float*)d_in[9];
  const float* f2bi = (const float*)d_in[10];
  const float* l1w  = (const float*)d_in[11];
  const float* l1b  = (const float*)d_in[12];
  const float* l2w  = (const float*)d_in[13];
  const float* l2b  = (const float*)d_in[14];
  const float* lnfw = (const float*)d_in[15];
  const float* lnfb = (const float*)d_in[16];

  char* ws = (char*)d_ws;
  size_t off = 0;
  auto take = [&](size_t bytes) -> void* {
    void* p = ws + off;
    off += (bytes + 255) & ~(size_t)255;
    return p;
  };
  ushort* wte_b = (ushort*)take((size_t)VV * DDIM * 2);
  ushort* aw_b  = (ushort*)take((size_t)LL * 3 * DDIM * DDIM * 2);
  ushort* pw_b  = (ushort*)take((size_t)LL * DDIM * DDIM * 2);
  ushort* fw_b  = (ushort*)take((size_t)LL * FF * DDIM * 2);
  ushort* f2w_b = (ushort*)take((size_t)LL * DDIM * FF * 2);
  ushort* xb    = (ushort*)take((size_t)MM * DDIM * 2);
  ushort* qkv_b = (ushort*)take((size_t)MM * 3 * DDIM * 2);
  ushort* yb    = (ushort*)take((size_t)MM * DDIM * 2);
  ushort* tmp_b = (ushort*)take((size_t)2 * MM * DDIM * 2);  // 2 bf16 split-K planes
  ushort* hb    = (ushort*)take((size_t)MM * FF * 2);

  cvt_all<<<dim3((unsigned)(CW4 / 4 / 256)), dim3(256), 0, stream>>>(
      wte, aw, pw, fw, f2w, wte_b);

  embed_kernel<<<dim3(MM), dim3(128), 0, stream>>>(idx, wte, wpe, xb);

  for (int l = 0; l < LL; ++l) {
    gemm_bt64<0, 1, 128, 64, 1, 512><<<dim3(24, 24), dim3(512), 0, stream>>>(
        xb, aw_b + (size_t)l * 3 * DDIM * DDIM, ab + (size_t)l * 3 * DDIM, qkv_b, 3 * DDIM, DDIM);
    attn_mfma<<<dim3(TT / 64, BB * 8), dim3(256), 0, stream>>>(qkv_b, yb);
    gemm_bt64<0, 1, 64, 64, 2, 256><<<dim3(8, 48, 2), dim3(256), 0, stream>>>(
        yb, pw_b + (size_t)l * DDIM * DDIM, pb + (size_t)l * DDIM, tmp_b, DDIM, DDIM);
    add_ln<2><<<dim3(MM / 4), dim3(256), 0, stream>>>(
        xb, tmp_b, l1w + (size_t)l * DDIM, l1b + (size_t)l * DDIM, xb);
    gemm_bt64<1, 1, 128, 64, 1, 512><<<dim3(32, 24), dim3(512), 0, stream>>>(
        xb, fw_b + (size_t)l * FF * DDIM, fb + (size_t)l * FF, hb, FF, DDIM);
    gemm_bt64<0, 1, 64, 64, 2, 256><<<dim3(8, 48, 2), dim3(256), 0, stream>>>(
        hb, f2w_b + (size_t)l * DDIM * FF, f2bi + (size_t)l * DDIM, tmp_b, DDIM, FF);
    add_ln<2><<<dim3(MM / 4), dim3(256), 0, stream>>>(
        xb, tmp_b, l2w + (size_t)l * DDIM, l2b + (size_t)l * DDIM, xb);
  }
  add_ln<0><<<dim3(MM / 4), dim3(256), 0, stream>>>(xb, nullptr, lnfw, lnfb, xb);

  gemm_head<<<dim3((VV / 128) * 24), dim3(256), 0, stream>>>(
      xb, wte_b, (float*)d_out, VV, DDIM);
}